// Round 11
// baseline (265.592 us; speedup 1.0000x reference)
//
#include <hip/hip_runtime.h>
#include <cstdint>
#include <cstddef>

#define B_ 2
#define T_ 2048
#define C_ 768
#define H_ 12
#define D_ 64

typedef __attribute__((ext_vector_type(8))) short s16x8;
typedef __attribute__((ext_vector_type(4))) float fx4;

static __device__ __forceinline__ unsigned short f2bf(float f) {
  unsigned u = __builtin_bit_cast(unsigned, f);
  unsigned r = u + 0x7fffu + ((u >> 16) & 1u);
  return (unsigned short)(r >> 16);
}
static __device__ __forceinline__ unsigned short f2bf_trunc(float f) {
  return (unsigned short)(__builtin_bit_cast(unsigned, f) >> 16);
}

static __device__ __forceinline__ void glds16(const unsigned short* g, unsigned short* l) {
  __builtin_amdgcn_global_load_lds(
      (const __attribute__((address_space(1))) void*)(g),
      (__attribute__((address_space(3))) void*)(l), 16, 0, 0);
}

// ---------------- fused prep: 4 weight transposes + LN1 in one launch -------
__global__ __launch_bounds__(256) void prep(
    const float* __restrict__ Wattn, const float* __restrict__ Wcproj,
    const float* __restrict__ Wfc, const float* __restrict__ Wmproj,
    unsigned short* __restrict__ WattnT, unsigned short* __restrict__ WcprojT,
    unsigned short* __restrict__ WfcT, unsigned short* __restrict__ WmprojT,
    const float* __restrict__ X, const float* __restrict__ g,
    const float* __restrict__ bb, unsigned short* __restrict__ O) {
  __shared__ float tile[32][33];
  __shared__ float ps[8];
  int bid = blockIdx.x, tid = threadIdx.x;
  if (bid < 6912) {
    const float* W; unsigned short* Wt; int R, C, idx;
    if (bid < 1728)      { W = Wattn;  Wt = WattnT;  R = 768;  C = 2304; idx = bid; }
    else if (bid < 2304) { W = Wcproj; Wt = WcprojT; R = 768;  C = 768;  idx = bid - 1728; }
    else if (bid < 4608) { W = Wfc;    Wt = WfcT;    R = 768;  C = 3072; idx = bid - 2304; }
    else                 { W = Wmproj; Wt = WmprojT; R = 3072; C = 768;  idx = bid - 4608; }
    int ct = C >> 5;
    int c0 = (idx % ct) * 32, r0 = (idx / ct) * 32;
    int tx = tid & 31, ty = tid >> 5;
#pragma unroll
    for (int i = 0; i < 4; ++i)
      tile[ty + i * 8][tx] = W[(size_t)(r0 + ty + i * 8) * C + (c0 + tx)];
    __syncthreads();
#pragma unroll
    for (int i = 0; i < 4; ++i)
      Wt[(size_t)(c0 + ty + i * 8) * R + (r0 + tx)] = f2bf(tile[tx][ty + i * 8]);
  } else {
    int row = bid - 6912;
    const float* xr = X + (size_t)row * C_;
    float v0 = xr[tid], v1 = xr[tid + 256], v2 = xr[tid + 512];
    float s = v0 + v1 + v2;
    float s2 = v0 * v0 + v1 * v1 + v2 * v2;
#pragma unroll
    for (int off = 1; off < 64; off <<= 1) {
      s += __shfl_xor(s, off);
      s2 += __shfl_xor(s2, off);
    }
    int wv = tid >> 6;
    if ((tid & 63) == 0) { ps[wv] = s; ps[wv + 4] = s2; }
    __syncthreads();
    s = ps[0] + ps[1] + ps[2] + ps[3];
    s2 = ps[4] + ps[5] + ps[6] + ps[7];
    float mu = s * (1.f / C_);
    float var = s2 * (1.f / C_) - mu * mu;
    float rstd = rsqrtf(var + 1e-5f);
    unsigned short* orow = O + (size_t)row * C_;
    orow[tid]       = f2bf((v0 - mu) * rstd * g[tid]       + bb[tid]);
    orow[tid + 256] = f2bf((v1 - mu) * rstd * g[tid + 256] + bb[tid + 256]);
    orow[tid + 512] = f2bf((v2 - mu) * rstd * g[tid + 512] + bb[tid + 512]);
  }
}

// ---------------- layernorm fp32 -> bf16 ------------------------------------
__global__ __launch_bounds__(256) void layernorm_bf16(
    const float* __restrict__ X, const float* __restrict__ g,
    const float* __restrict__ bb, unsigned short* __restrict__ O) {
  int row = blockIdx.x, tid = threadIdx.x;
  const float* xr = X + (size_t)row * C_;
  float v0 = xr[tid], v1 = xr[tid + 256], v2 = xr[tid + 512];
  float s = v0 + v1 + v2;
  float s2 = v0 * v0 + v1 * v1 + v2 * v2;
#pragma unroll
  for (int off = 1; off < 64; off <<= 1) {
    s += __shfl_xor(s, off);
    s2 += __shfl_xor(s2, off);
  }
  __shared__ float ps[8];
  int wv = tid >> 6;
  if ((tid & 63) == 0) { ps[wv] = s; ps[wv + 4] = s2; }
  __syncthreads();
  s = ps[0] + ps[1] + ps[2] + ps[3];
  s2 = ps[4] + ps[5] + ps[6] + ps[7];
  float mu = s * (1.f / C_);
  float var = s2 * (1.f / C_) - mu * mu;
  float rstd = rsqrtf(var + 1e-5f);
  unsigned short* orow = O + (size_t)row * C_;
  orow[tid]       = f2bf((v0 - mu) * rstd * g[tid]       + bb[tid]);
  orow[tid + 256] = f2bf((v1 - mu) * rstd * g[tid + 256] + bb[tid + 256]);
  orow[tid + 512] = f2bf((v2 - mu) * rstd * g[tid + 512] + bb[tid + 512]);
}

// ---------------- reduce: out = x1 + P0 + P1 + bias (float4) ----------------
// one float4 per thread; 4096*768 fp32 = 786432 float4 -> grid 3072 x 256
__global__ __launch_bounds__(256) void reduce_out(
    const float* __restrict__ x1, const float* __restrict__ P,
    const float* __restrict__ bias, float* __restrict__ out) {
  int idx = blockIdx.x * 256 + threadIdx.x;
  float4 a = ((const float4*)x1)[idx];
  float4 p = ((const float4*)P)[idx];
  float4 q = ((const float4*)(P + (size_t)4096 * 768))[idx];
  float4 b = ((const float4*)bias)[idx % 192];
  float4 o;
  o.x = a.x + p.x + q.x + b.x;
  o.y = a.y + p.y + q.y + b.y;
  o.z = a.z + p.z + q.z + b.z;
  o.w = a.w + p.w + q.w + b.w;
  ((float4*)out)[idx] = o;
}

// ---------------- double-buffered GEMM: C = A[M,K-chunk] * Bt^T + bias ------
// 256 threads = 4 waves (2x2); glds width-16 staging; LDS double buffer.
// BK==64: XOR-swizzle chunk ^ (row&7)   (row stride 128B = 32 banks; r4 fix)
// BK==32: XOR-swizzle chunk ^ ((row>>1)&3) (row stride 64B = 16 banks; the
//         16 fragment lanes otherwise collapse to two 8-way chunk conflicts)
// MODE 0: QKV scatter; MODE 1: resid+bias fp32 (m-fastest grid);
// MODE 2: tanh-gelu bf16; MODE 3: raw fp32 partial to outF + z*M*N.
template <int BM, int BN, int BK, int MODE>
__global__ __launch_bounds__(256) void gemm_db(
    const unsigned short* __restrict__ A, const unsigned short* __restrict__ Bt,
    const float* __restrict__ bias, const float* __restrict__ resid,
    float* __restrict__ outF, unsigned short* __restrict__ outB,
    unsigned short* __restrict__ qO, unsigned short* __restrict__ kO,
    unsigned short* __restrict__ vtO, int M, int N, int K, int KC) {
  constexpr int AT = BM / 32;
  constexpr int BT = BN / 32;
  constexpr int KS = BK / 32;
  constexpr int ACH = BM * BK / 8;
  constexpr int BCH = BN * BK / 8;
  constexpr int ASZ = BM * BK, BSZ = BN * BK;
  constexpr bool SWIZ = (BK == 64);
  constexpr bool SWIZ32 = (BK == 32);
  __shared__ __align__(16) unsigned short As[2 * ASZ];
  __shared__ __align__(16) unsigned short Bs[2 * BSZ];
  int tid = threadIdx.x;
  int wv = tid >> 6, lane = tid & 63, quad = lane >> 4, l15 = lane & 15;
  int wm = wv >> 1, wn = wv & 1;
  int m0, n0;
  if (MODE == 1 || MODE == 3) { m0 = blockIdx.x * BM; n0 = blockIdx.y * BN; }
  else                        { n0 = blockIdx.x * BN; m0 = blockIdx.y * BM; }
  const unsigned short* Ak = A + (size_t)blockIdx.z * KC;
  const unsigned short* Bk = Bt + (size_t)blockIdx.z * KC;
  fx4 acc[AT][BT];
#pragma unroll
  for (int i = 0; i < AT; ++i)
#pragma unroll
    for (int j = 0; j < BT; ++j) acc[i][j] = fx4{0.f, 0.f, 0.f, 0.f};

  int nk = KC / BK;
#pragma unroll
  for (int i0 = 0; i0 < ACH; i0 += 256)
    if (ACH - i0 >= 256 || tid < ACH - i0) {
      int e = (i0 + tid) * 8;
      int row = e / BK, cg = (e & (BK - 1)) >> 3;
      if (SWIZ) cg ^= (row & 7);
      if (SWIZ32) cg ^= ((row >> 1) & 3);
      glds16(&Ak[(size_t)(m0 + row) * K + (cg << 3)], &As[(i0 + (tid & ~63)) * 8]);
    }
#pragma unroll
  for (int i0 = 0; i0 < BCH; i0 += 256)
    if (BCH - i0 >= 256 || tid < BCH - i0) {
      int e = (i0 + tid) * 8;
      int row = e / BK, cg = (e & (BK - 1)) >> 3;
      if (SWIZ) cg ^= (row & 7);
      if (SWIZ32) cg ^= ((row >> 1) & 3);
      glds16(&Bk[(size_t)(n0 + row) * K + (cg << 3)], &Bs[(i0 + (tid & ~63)) * 8]);
    }
  for (int kt = 0; kt < nk; ++kt) {
    int cur = kt & 1;
    __syncthreads();
    if (kt + 1 < nk) {
      int kb = (kt + 1) * BK;
      int nxt = cur ^ 1;
#pragma unroll
      for (int i0 = 0; i0 < ACH; i0 += 256)
        if (ACH - i0 >= 256 || tid < ACH - i0) {
          int e = (i0 + tid) * 8;
          int row = e / BK, cg = (e & (BK - 1)) >> 3;
          if (SWIZ) cg ^= (row & 7);
          if (SWIZ32) cg ^= ((row >> 1) & 3);
          glds16(&Ak[(size_t)(m0 + row) * K + kb + (cg << 3)],
                 &As[nxt * ASZ + (i0 + (tid & ~63)) * 8]);
        }
#pragma unroll
      for (int i0 = 0; i0 < BCH; i0 += 256)
        if (BCH - i0 >= 256 || tid < BCH - i0) {
          int e = (i0 + tid) * 8;
          int row = e / BK, cg = (e & (BK - 1)) >> 3;
          if (SWIZ) cg ^= (row & 7);
          if (SWIZ32) cg ^= ((row >> 1) & 3);
          glds16(&Bk[(size_t)(n0 + row) * K + kb + (cg << 3)],
                 &Bs[nxt * BSZ + (i0 + (tid & ~63)) * 8]);
        }
    }
#pragma unroll
    for (int ks = 0; ks < KS; ++ks) {
      s16x8 af[AT], bf[BT];
#pragma unroll
      for (int mt = 0; mt < AT; ++mt) {
        int r = wm * (BM / 2) + mt * 16 + l15;
        int cg = (ks * 32 + quad * 8) >> 3;
        if (SWIZ) cg ^= (r & 7);
        if (SWIZ32) cg ^= ((r >> 1) & 3);
        af[mt] = *(const s16x8*)&As[cur * ASZ + r * BK + (cg << 3)];
      }
#pragma unroll
      for (int nt = 0; nt < BT; ++nt) {
        int r = wn * (BN / 2) + nt * 16 + l15;
        int cg = (ks * 32 + quad * 8) >> 3;
        if (SWIZ) cg ^= (r & 7);
        if (SWIZ32) cg ^= ((r >> 1) & 3);
        bf[nt] = *(const s16x8*)&Bs[cur * BSZ + r * BK + (cg << 3)];
      }
#pragma unroll
      for (int mt = 0; mt < AT; ++mt)
#pragma unroll
        for (int nt = 0; nt < BT; ++nt)
          acc[mt][nt] = __builtin_amdgcn_mfma_f32_16x16x32_bf16(af[mt], bf[nt], acc[mt][nt], 0, 0, 0);
    }
  }

#pragma unroll
  for (int mt = 0; mt < AT; ++mt)
#pragma unroll
    for (int nt = 0; nt < BT; ++nt) {
      int mb = m0 + wm * (BM / 2) + mt * 16 + quad * 4;
      int n = n0 + wn * (BN / 2) + nt * 16 + l15;
      if (MODE == 0) {
        int which = n / C_;
        int within = n - which * C_;
        int hd = within >> 6, d = within & 63;
        int bbx = mb >> 11, t = mb & 2047;
        size_t bh = (size_t)(bbx * H_ + hd);
        float b = bias[n];
        if (which == 2) {
          unsigned v01 = (unsigned)f2bf(acc[mt][nt][0] + b) |
                         ((unsigned)f2bf(acc[mt][nt][1] + b) << 16);
          unsigned v23 = (unsigned)f2bf(acc[mt][nt][2] + b) |
                         ((unsigned)f2bf(acc[mt][nt][3] + b) << 16);
          *(uint2*)&vtO[(bh * D_ + d) * T_ + t] = uint2{v01, v23};
        } else {
          unsigned short* dst = (which == 0) ? qO : kO;
#pragma unroll
          for (int r = 0; r < 4; ++r)
            dst[(bh * T_ + t + r) * D_ + d] = f2bf(acc[mt][nt][r] + b);
        }
      } else if (MODE == 1) {
#pragma unroll
        for (int r = 0; r < 4; ++r) {
          int m = mb + r;
          float v = acc[mt][nt][r] + bias[n];
          outF[(size_t)m * N + n] = resid[(size_t)m * N + n] + v;
        }
      } else if (MODE == 3) {
        float* P = outF + (size_t)blockIdx.z * M * N;
#pragma unroll
        for (int r = 0; r < 4; ++r)
          P[(size_t)(mb + r) * N + n] = acc[mt][nt][r];
      } else {
        // tanh-form gelu: x*sigmoid(2*0.79788456*(x+0.044715 x^3)); abs err ~3e-4
#pragma unroll
        for (int r = 0; r < 4; ++r) {
          int m = mb + r;
          float v = acc[mt][nt][r] + bias[n];
          float w2 = v * v;
          float u2 = v * (-1.5957691216f - 0.0713548163f * w2);  // -2*c1*(x+c2 x^3)
          float gl = v * __frcp_rn(1.f + __expf(u2));
          outB[(size_t)m * N + n] = f2bf_trunc(gl);
        }
      }
    }
}

// ---------------- fused causal flash attention (128-key iterations) ---------
// LDS-staged K/V, register prefetch, balanced qt schedule (r7). 128 keys per
// barrier pair (vs 64) halves the barrier count; always-on causal mask covers
// the padded half-tile when qt is even (overread tile qt+1 <= 31, in-bounds).
__global__ __launch_bounds__(256) void attn_fused(
    const unsigned short* __restrict__ Q, const unsigned short* __restrict__ Kg,
    const unsigned short* __restrict__ Vt, unsigned short* __restrict__ Y) {
  __shared__ __align__(16) unsigned short Ks[128 * 72];
  __shared__ __align__(16) unsigned short Vs[64 * 136];
  __shared__ __align__(16) unsigned short Ps[4][16 * 136];
  int tid = threadIdx.x;
  int wv = tid >> 6, lane = tid & 63, quad = lane >> 4, l15 = lane & 15;
  int l = blockIdx.x;
  int w = l >> 8, c = l & 255;
  int i = c & 31;
  int bh = w * 8 + (c >> 5);
  int qt;
  if (w == 0)      qt = i;
  else if (w == 1) qt = (i + 16) & 31;
  else             qt = (i < 16) ? (30 - 2 * i) : (63 - 2 * i);
  int bbx = bh / H_, hh = bh - bbx * H_;
  int q0 = qt * 64;
  size_t base = (size_t)bh * T_ * D_;
  size_t vbase = (size_t)bh * D_ * T_;
  int qrow = q0 + wv * 16 + l15;
  s16x8 qf0 = *(const s16x8*)&Q[base + (size_t)qrow * D_ + quad * 8];
  s16x8 qf1 = *(const s16x8*)&Q[base + (size_t)qrow * D_ + 32 + quad * 8];
  float lsum[4];
  fx4 oacc[4];
#pragma unroll
  for (int t = 0; t < 4; ++t) {
    lsum[t] = 0.f;
    oacc[t] = fx4{0.f, 0.f, 0.f, 0.f};
  }
  int nDbl = (qt >> 1) + 1;
  int r0s = tid >> 3;          // 0..31
  int c8 = (tid & 7) * 8;      // 0..56
  uint4 ka0, ka1, ka2, ka3, va0, va1, va2, va3;
  {
    const unsigned short* Kp = Kg + base;
    ka0 = *(const uint4*)&Kp[(size_t)r0s * D_ + c8];
    ka1 = *(const uint4*)&Kp[(size_t)(r0s + 32) * D_ + c8];
    ka2 = *(const uint4*)&Kp[(size_t)(r0s + 64) * D_ + c8];
    ka3 = *(const uint4*)&Kp[(size_t)(r0s + 96) * D_ + c8];
    const unsigned short* Vp = Vt + vbase;
    va0 = *(const uint4*)&Vp[(size_t)r0s * T_ + c8];
    va1 = *(const uint4*)&Vp[(size_t)r0s * T_ + 64 + c8];
    va2 = *(const uint4*)&Vp[(size_t)(r0s + 32) * T_ + c8];
    va3 = *(const uint4*)&Vp[(size_t)(r0s + 32) * T_ + 64 + c8];
  }
  unsigned short* pw = &Ps[wv][0];
  for (int kb = 0; kb < nDbl; ++kb) {
    int k0 = kb * 128;
    __syncthreads();
    *(uint4*)&Ks[r0s * 72 + c8] = ka0;
    *(uint4*)&Ks[(r0s + 32) * 72 + c8] = ka1;
    *(uint4*)&Ks[(r0s + 64) * 72 + c8] = ka2;
    *(uint4*)&Ks[(r0s + 96) * 72 + c8] = ka3;
    *(uint4*)&Vs[r0s * 136 + c8] = va0;
    *(uint4*)&Vs[r0s * 136 + 64 + c8] = va1;
    *(uint4*)&Vs[(r0s + 32) * 136 + c8] = va2;
    *(uint4*)&Vs[(r0s + 32) * 136 + 64 + c8] = va3;
    __syncthreads();
    if (kb + 1 < nDbl) {
      int kn = k0 + 128;
      const unsigned short* Kp = Kg + base + (size_t)kn * D_;
      ka0 = *(const uint4*)&Kp[(size_t)r0s * D_ + c8];
      ka1 = *(const uint4*)&Kp[(size_t)(r0s + 32) * D_ + c8];
      ka2 = *(const uint4*)&Kp[(size_t)(r0s + 64) * D_ + c8];
      ka3 = *(const uint4*)&Kp[(size_t)(r0s + 96) * D_ + c8];
      const unsigned short* Vp = Vt + vbase + kn;
      va0 = *(const uint4*)&Vp[(size_t)r0s * T_ + c8];
      va1 = *(const uint4*)&Vp[(size_t)r0s * T_ + 64 + c8];
      va2 = *(const uint4*)&Vp[(size_t)(r0s + 32) * T_ + c8];
      va3 = *(const uint4*)&Vp[(size_t)(r0s + 32) * T_ + 64 + c8];
    }
    fx4 sc[8];
#pragma unroll
    for (int nt = 0; nt < 8; ++nt) {
      sc[nt] = fx4{0.f, 0.f, 0.f, 0.f};
      s16x8 kf0 = *(const s16x8*)&Ks[(nt * 16 + l15) * 72 + quad * 8];
      s16x8 kf1 = *(const s16x8*)&Ks[(nt * 16 + l15) * 72 + 32 + quad * 8];
      sc[nt] = __builtin_amdgcn_mfma_f32_16x16x32_bf16(qf0, kf0, sc[nt], 0, 0, 0);
      sc[nt] = __builtin_amdgcn_mfma_f32_16x16x32_bf16(qf1, kf1, sc[nt], 0, 0, 0);
    }
#pragma unroll
    for (int nt = 0; nt < 8; ++nt)
#pragma unroll
      for (int r = 0; r < 4; ++r) {
        int key = k0 + nt * 16 + l15;
        int row = q0 + wv * 16 + quad * 4 + r;
        float p = (key > row) ? 0.f : __expf(sc[nt][r] * 0.125f);
        lsum[r] += p;
        pw[(quad * 4 + r) * 136 + nt * 16 + l15] = f2bf_trunc(p);
      }
    s16x8 pa[4];
#pragma unroll
    for (int ch = 0; ch < 4; ++ch)
      pa[ch] = *(const s16x8*)&pw[l15 * 136 + ch * 32 + quad * 8];
#pragma unroll
    for (int nt = 0; nt < 4; ++nt) {
#pragma unroll
      for (int ch = 0; ch < 4; ++ch) {
        s16x8 vf = *(const s16x8*)&Vs[(nt * 16 + l15) * 136 + ch * 32 + quad * 8];
        oacc[nt] = __builtin_amdgcn_mfma_f32_16x16x32_bf16(pa[ch], vf, oacc[nt], 0, 0, 0);
      }
    }
  }
#pragma unroll
  for (int r = 0; r < 4; ++r) {
#pragma unroll
    for (int off = 1; off < 16; off <<= 1) lsum[r] += __shfl_xor(lsum[r], off);
  }
#pragma unroll
  for (int nt = 0; nt < 4; ++nt)
#pragma unroll
    for (int r = 0; r < 4; ++r) {
      float o = oacc[nt][r] / lsum[r];
      int token = bbx * T_ + q0 + wv * 16 + quad * 4 + r;
      Y[(size_t)token * C_ + hh * D_ + nt * 16 + l15] = f2bf(o);
    }
}

// ---------------- launcher --------------------------------------------------
extern "C" void kernel_launch(void* const* d_in, const int* in_sizes, int n_in,
                              void* d_out, int out_size, void* d_ws, size_t ws_size,
                              hipStream_t stream) {
  const float* x      = (const float*)d_in[0];
  const float* ln1g   = (const float*)d_in[1];
  const float* ln1b   = (const float*)d_in[2];
  const float* Wattn  = (const float*)d_in[3];
  const float* battn  = (const float*)d_in[4];
  const float* Wcproj = (const float*)d_in[5];
  const float* bcproj = (const float*)d_in[6];
  const float* ln2g   = (const float*)d_in[7];
  const float* ln2b   = (const float*)d_in[8];
  const float* Wfc    = (const float*)d_in[9];
  const float* bfc    = (const float*)d_in[10];
  const float* Wmproj = (const float*)d_in[11];
  const float* bmproj = (const float*)d_in[12];
  float* out = (float*)d_out;
  char* ws = (char*)d_ws;

  unsigned short* WattnT  = (unsigned short*)(ws + 0);          // 2304x768 bf16
  unsigned short* WcprojT = (unsigned short*)(ws + 3538944);    // 768x768
  unsigned short* WfcT    = (unsigned short*)(ws + 4718592);    // 3072x768
  unsigned short* WmprojT = (unsigned short*)(ws + 9437184);    // 768x3072
  unsigned short* hbuf    = (unsigned short*)(ws + 14155776);   // 4096x768 bf16
  unsigned short* Qb      = (unsigned short*)(ws + 20447232);   // [24,2048,64]
  unsigned short* Kb      = (unsigned short*)(ws + 26738688);   // [24,2048,64]
  unsigned short* Vtb     = (unsigned short*)(ws + 33030144);   // [24,64,2048]
  unsigned short* Yb      = (unsigned short*)(ws + 39321600);   // 4096x768 bf16
  float*          x1      = (float*)(ws + 45613056);            // 4096x768 fp32
  unsigned short* Ab      = (unsigned short*)(ws + 58195968);   // 4096x3072 bf16
  // split-K partials overlay Qb..Yb (dead after cproj): 2 x 4096x768 fp32
  float*          Pbuf    = (float*)(ws + 20447232);

  prep<<<11008, 256, 0, stream>>>(Wattn, Wcproj, Wfc, Wmproj,
                                  WattnT, WcprojT, WfcT, WmprojT,
                                  x, ln1g, ln1b, hbuf);

  // qkv: BM=128 BN=96 BK=32 (swizzled) -> 768 blocks, 3/CU fully resident
  gemm_db<128, 96, 32, 0><<<dim3(24, 32), 256, 0, stream>>>(
      hbuf, WattnT, battn, nullptr, nullptr, nullptr, Qb, Kb, Vtb,
      4096, 2304, 768, 768);

  attn_fused<<<768, 256, 0, stream>>>(Qb, Kb, Vtb, Yb);

  // cproj: BM=128 BN=64 BK=64 swizzled, 384 blocks
  gemm_db<128, 64, 64, 1><<<dim3(32, 12), 256, 0, stream>>>(
      Yb, WcprojT, bcproj, x, x1, nullptr, nullptr, nullptr, nullptr,
      4096, 768, 768, 768);

  layernorm_bf16<<<4096, 256, 0, stream>>>(x1, ln2g, ln2b, hbuf);

  // fc: BM=128 BN=128 BK=32 (swizzled), tanh-gelu epilogue
  gemm_db<128, 128, 32, 2><<<dim3(24, 32), 256, 0, stream>>>(
      hbuf, WfcT, bfc, nullptr, nullptr, Ab, nullptr, nullptr, nullptr,
      4096, 3072, 768, 768);

  // mproj split-K=2: 768 blocks = 3/CU resident uniform, K chunks of 1536
  gemm_db<128, 64, 64, 3><<<dim3(32, 12, 2), 256, 0, stream>>>(
      Ab, WmprojT, bmproj, nullptr, Pbuf, nullptr, nullptr, nullptr, nullptr,
      4096, 768, 3072, 1536);

  // out = x1 + P0 + P1 + bias  (786432 float4 / 256 per block = 3072 blocks)
  reduce_out<<<3072, 256, 0, stream>>>(x1, Pbuf, bmproj, out);
}

// Round 12
// 264.949 us; speedup vs baseline: 1.0024x; 1.0024x over previous
//
#include <hip/hip_runtime.h>
#include <cstdint>
#include <cstddef>

#define B_ 2
#define T_ 2048
#define C_ 768
#define H_ 12
#define D_ 64

typedef __attribute__((ext_vector_type(8))) short s16x8;
typedef __attribute__((ext_vector_type(4))) float fx4;

static __device__ __forceinline__ unsigned short f2bf(float f) {
  unsigned u = __builtin_bit_cast(unsigned, f);
  unsigned r = u + 0x7fffu + ((u >> 16) & 1u);
  return (unsigned short)(r >> 16);
}
static __device__ __forceinline__ unsigned short f2bf_trunc(float f) {
  return (unsigned short)(__builtin_bit_cast(unsigned, f) >> 16);
}

static __device__ __forceinline__ void glds16(const unsigned short* g, unsigned short* l) {
  __builtin_amdgcn_global_load_lds(
      (const __attribute__((address_space(1))) void*)(g),
      (__attribute__((address_space(3))) void*)(l), 16, 0, 0);
}

// ---------------- fused prep: 4 weight transposes + LN1 in one launch -------
__global__ __launch_bounds__(256) void prep(
    const float* __restrict__ Wattn, const float* __restrict__ Wcproj,
    const float* __restrict__ Wfc, const float* __restrict__ Wmproj,
    unsigned short* __restrict__ WattnT, unsigned short* __restrict__ WcprojT,
    unsigned short* __restrict__ WfcT, unsigned short* __restrict__ WmprojT,
    const float* __restrict__ X, const float* __restrict__ g,
    const float* __restrict__ bb, unsigned short* __restrict__ O) {
  __shared__ float tile[32][33];
  __shared__ float ps[8];
  int bid = blockIdx.x, tid = threadIdx.x;
  if (bid < 6912) {
    const float* W; unsigned short* Wt; int R, C, idx;
    if (bid < 1728)      { W = Wattn;  Wt = WattnT;  R = 768;  C = 2304; idx = bid; }
    else if (bid < 2304) { W = Wcproj; Wt = WcprojT; R = 768;  C = 768;  idx = bid - 1728; }
    else if (bid < 4608) { W = Wfc;    Wt = WfcT;    R = 768;  C = 3072; idx = bid - 2304; }
    else                 { W = Wmproj; Wt = WmprojT; R = 3072; C = 768;  idx = bid - 4608; }
    int ct = C >> 5;
    int c0 = (idx % ct) * 32, r0 = (idx / ct) * 32;
    int tx = tid & 31, ty = tid >> 5;
#pragma unroll
    for (int i = 0; i < 4; ++i)
      tile[ty + i * 8][tx] = W[(size_t)(r0 + ty + i * 8) * C + (c0 + tx)];
    __syncthreads();
#pragma unroll
    for (int i = 0; i < 4; ++i)
      Wt[(size_t)(c0 + ty + i * 8) * R + (r0 + tx)] = f2bf(tile[tx][ty + i * 8]);
  } else {
    int row = bid - 6912;
    const float* xr = X + (size_t)row * C_;
    float v0 = xr[tid], v1 = xr[tid + 256], v2 = xr[tid + 512];
    float s = v0 + v1 + v2;
    float s2 = v0 * v0 + v1 * v1 + v2 * v2;
#pragma unroll
    for (int off = 1; off < 64; off <<= 1) {
      s += __shfl_xor(s, off);
      s2 += __shfl_xor(s2, off);
    }
    int wv = tid >> 6;
    if ((tid & 63) == 0) { ps[wv] = s; ps[wv + 4] = s2; }
    __syncthreads();
    s = ps[0] + ps[1] + ps[2] + ps[3];
    s2 = ps[4] + ps[5] + ps[6] + ps[7];
    float mu = s * (1.f / C_);
    float var = s2 * (1.f / C_) - mu * mu;
    float rstd = rsqrtf(var + 1e-5f);
    unsigned short* orow = O + (size_t)row * C_;
    orow[tid]       = f2bf((v0 - mu) * rstd * g[tid]       + bb[tid]);
    orow[tid + 256] = f2bf((v1 - mu) * rstd * g[tid + 256] + bb[tid + 256]);
    orow[tid + 512] = f2bf((v2 - mu) * rstd * g[tid + 512] + bb[tid + 512]);
  }
}

// ---------------- layernorm fp32 -> bf16 ------------------------------------
__global__ __launch_bounds__(256) void layernorm_bf16(
    const float* __restrict__ X, const float* __restrict__ g,
    const float* __restrict__ bb, unsigned short* __restrict__ O) {
  int row = blockIdx.x, tid = threadIdx.x;
  const float* xr = X + (size_t)row * C_;
  float v0 = xr[tid], v1 = xr[tid + 256], v2 = xr[tid + 512];
  float s = v0 + v1 + v2;
  float s2 = v0 * v0 + v1 * v1 + v2 * v2;
#pragma unroll
  for (int off = 1; off < 64; off <<= 1) {
    s += __shfl_xor(s, off);
    s2 += __shfl_xor(s2, off);
  }
  __shared__ float ps[8];
  int wv = tid >> 6;
  if ((tid & 63) == 0) { ps[wv] = s; ps[wv + 4] = s2; }
  __syncthreads();
  s = ps[0] + ps[1] + ps[2] + ps[3];
  s2 = ps[4] + ps[5] + ps[6] + ps[7];
  float mu = s * (1.f / C_);
  float var = s2 * (1.f / C_) - mu * mu;
  float rstd = rsqrtf(var + 1e-5f);
  unsigned short* orow = O + (size_t)row * C_;
  orow[tid]       = f2bf((v0 - mu) * rstd * g[tid]       + bb[tid]);
  orow[tid + 256] = f2bf((v1 - mu) * rstd * g[tid + 256] + bb[tid + 256]);
  orow[tid + 512] = f2bf((v2 - mu) * rstd * g[tid + 512] + bb[tid + 512]);
}

// ---------------- reduce: out = x1 + P0 + P1 + bias (float4) ----------------
// one float4 per thread; 4096*768 fp32 = 786432 float4 -> grid 3072 x 256
__global__ __launch_bounds__(256) void reduce_out(
    const float* __restrict__ x1, const float* __restrict__ P,
    const float* __restrict__ bias, float* __restrict__ out) {
  int idx = blockIdx.x * 256 + threadIdx.x;
  float4 a = ((const float4*)x1)[idx];
  float4 p = ((const float4*)P)[idx];
  float4 q = ((const float4*)(P + (size_t)4096 * 768))[idx];
  float4 b = ((const float4*)bias)[idx % 192];
  float4 o;
  o.x = a.x + p.x + q.x + b.x;
  o.y = a.y + p.y + q.y + b.y;
  o.z = a.z + p.z + q.z + b.z;
  o.w = a.w + p.w + q.w + b.w;
  ((float4*)out)[idx] = o;
}

// ---------------- double-buffered GEMM: C = A[M,K-chunk] * Bt^T + bias ------
// 256 threads = 4 waves (2x2); glds width-16 staging; LDS double buffer.
// BK==64: XOR-swizzle chunk ^ (row&7) (row stride 128B = 32 banks -> 16-way
// conflict without it; verified 0-conflict + faster, r5/r7).
// BK==32: NO swizzle — r11 measured it as a net loss (global-order
// degradation: FETCH +11%, VGPR +16; the 8-way LDS conflict it removes is
// hidden under the barrier stall, SQ_LDS_BANK_CONFLICT=0 gave no speedup).
// MODE 0: QKV scatter; MODE 1: resid+bias fp32 (m-fastest grid);
// MODE 2: tanh-gelu bf16; MODE 3: raw fp32 partial to outF + z*M*N.
template <int BM, int BN, int BK, int MODE>
__global__ __launch_bounds__(256) void gemm_db(
    const unsigned short* __restrict__ A, const unsigned short* __restrict__ Bt,
    const float* __restrict__ bias, const float* __restrict__ resid,
    float* __restrict__ outF, unsigned short* __restrict__ outB,
    unsigned short* __restrict__ qO, unsigned short* __restrict__ kO,
    unsigned short* __restrict__ vtO, int M, int N, int K, int KC) {
  constexpr int AT = BM / 32;
  constexpr int BT = BN / 32;
  constexpr int KS = BK / 32;
  constexpr int ACH = BM * BK / 8;
  constexpr int BCH = BN * BK / 8;
  constexpr int ASZ = BM * BK, BSZ = BN * BK;
  constexpr bool SWIZ = (BK == 64);
  __shared__ __align__(16) unsigned short As[2 * ASZ];
  __shared__ __align__(16) unsigned short Bs[2 * BSZ];
  int tid = threadIdx.x;
  int wv = tid >> 6, lane = tid & 63, quad = lane >> 4, l15 = lane & 15;
  int wm = wv >> 1, wn = wv & 1;
  int m0, n0;
  if (MODE == 1 || MODE == 3) { m0 = blockIdx.x * BM; n0 = blockIdx.y * BN; }
  else                        { n0 = blockIdx.x * BN; m0 = blockIdx.y * BM; }
  const unsigned short* Ak = A + (size_t)blockIdx.z * KC;
  const unsigned short* Bk = Bt + (size_t)blockIdx.z * KC;
  fx4 acc[AT][BT];
#pragma unroll
  for (int i = 0; i < AT; ++i)
#pragma unroll
    for (int j = 0; j < BT; ++j) acc[i][j] = fx4{0.f, 0.f, 0.f, 0.f};

  int nk = KC / BK;
#pragma unroll
  for (int i0 = 0; i0 < ACH; i0 += 256)
    if (ACH - i0 >= 256 || tid < ACH - i0) {
      int e = (i0 + tid) * 8;
      int row = e / BK, cg = (e & (BK - 1)) >> 3;
      if (SWIZ) cg ^= (row & 7);
      glds16(&Ak[(size_t)(m0 + row) * K + (cg << 3)], &As[(i0 + (tid & ~63)) * 8]);
    }
#pragma unroll
  for (int i0 = 0; i0 < BCH; i0 += 256)
    if (BCH - i0 >= 256 || tid < BCH - i0) {
      int e = (i0 + tid) * 8;
      int row = e / BK, cg = (e & (BK - 1)) >> 3;
      if (SWIZ) cg ^= (row & 7);
      glds16(&Bk[(size_t)(n0 + row) * K + (cg << 3)], &Bs[(i0 + (tid & ~63)) * 8]);
    }
  for (int kt = 0; kt < nk; ++kt) {
    int cur = kt & 1;
    __syncthreads();
    if (kt + 1 < nk) {
      int kb = (kt + 1) * BK;
      int nxt = cur ^ 1;
#pragma unroll
      for (int i0 = 0; i0 < ACH; i0 += 256)
        if (ACH - i0 >= 256 || tid < ACH - i0) {
          int e = (i0 + tid) * 8;
          int row = e / BK, cg = (e & (BK - 1)) >> 3;
          if (SWIZ) cg ^= (row & 7);
          glds16(&Ak[(size_t)(m0 + row) * K + kb + (cg << 3)],
                 &As[nxt * ASZ + (i0 + (tid & ~63)) * 8]);
        }
#pragma unroll
      for (int i0 = 0; i0 < BCH; i0 += 256)
        if (BCH - i0 >= 256 || tid < BCH - i0) {
          int e = (i0 + tid) * 8;
          int row = e / BK, cg = (e & (BK - 1)) >> 3;
          if (SWIZ) cg ^= (row & 7);
          glds16(&Bk[(size_t)(n0 + row) * K + kb + (cg << 3)],
                 &Bs[nxt * BSZ + (i0 + (tid & ~63)) * 8]);
        }
    }
#pragma unroll
    for (int ks = 0; ks < KS; ++ks) {
      s16x8 af[AT], bf[BT];
#pragma unroll
      for (int mt = 0; mt < AT; ++mt) {
        int r = wm * (BM / 2) + mt * 16 + l15;
        int cg = (ks * 32 + quad * 8) >> 3;
        if (SWIZ) cg ^= (r & 7);
        af[mt] = *(const s16x8*)&As[cur * ASZ + r * BK + (cg << 3)];
      }
#pragma unroll
      for (int nt = 0; nt < BT; ++nt) {
        int r = wn * (BN / 2) + nt * 16 + l15;
        int cg = (ks * 32 + quad * 8) >> 3;
        if (SWIZ) cg ^= (r & 7);
        bf[nt] = *(const s16x8*)&Bs[cur * BSZ + r * BK + (cg << 3)];
      }
#pragma unroll
      for (int mt = 0; mt < AT; ++mt)
#pragma unroll
        for (int nt = 0; nt < BT; ++nt)
          acc[mt][nt] = __builtin_amdgcn_mfma_f32_16x16x32_bf16(af[mt], bf[nt], acc[mt][nt], 0, 0, 0);
    }
  }

#pragma unroll
  for (int mt = 0; mt < AT; ++mt)
#pragma unroll
    for (int nt = 0; nt < BT; ++nt) {
      int mb = m0 + wm * (BM / 2) + mt * 16 + quad * 4;
      int n = n0 + wn * (BN / 2) + nt * 16 + l15;
      if (MODE == 0) {
        int which = n / C_;
        int within = n - which * C_;
        int hd = within >> 6, d = within & 63;
        int bbx = mb >> 11, t = mb & 2047;
        size_t bh = (size_t)(bbx * H_ + hd);
        float b = bias[n];
        if (which == 2) {
          unsigned v01 = (unsigned)f2bf(acc[mt][nt][0] + b) |
                         ((unsigned)f2bf(acc[mt][nt][1] + b) << 16);
          unsigned v23 = (unsigned)f2bf(acc[mt][nt][2] + b) |
                         ((unsigned)f2bf(acc[mt][nt][3] + b) << 16);
          *(uint2*)&vtO[(bh * D_ + d) * T_ + t] = uint2{v01, v23};
        } else {
          unsigned short* dst = (which == 0) ? qO : kO;
#pragma unroll
          for (int r = 0; r < 4; ++r)
            dst[(bh * T_ + t + r) * D_ + d] = f2bf(acc[mt][nt][r] + b);
        }
      } else if (MODE == 1) {
#pragma unroll
        for (int r = 0; r < 4; ++r) {
          int m = mb + r;
          float v = acc[mt][nt][r] + bias[n];
          outF[(size_t)m * N + n] = resid[(size_t)m * N + n] + v;
        }
      } else if (MODE == 3) {
        float* P = outF + (size_t)blockIdx.z * M * N;
#pragma unroll
        for (int r = 0; r < 4; ++r)
          P[(size_t)(mb + r) * N + n] = acc[mt][nt][r];
      } else {
        // tanh-form gelu: x*sigmoid(1.5957691*(x+0.044715 x^3)); abs err ~3e-4
#pragma unroll
        for (int r = 0; r < 4; ++r) {
          int m = mb + r;
          float v = acc[mt][nt][r] + bias[n];
          float w2 = v * v;
          float u2 = v * (-1.5957691216f - 0.0713548163f * w2);
          float gl = v * __frcp_rn(1.f + __expf(u2));
          outB[(size_t)m * N + n] = f2bf_trunc(gl);
        }
      }
    }
}

// ---------------- fused causal flash attention (128-key iterations) ---------
// LDS-staged K/V, register prefetch, balanced qt schedule (r7). 128 keys per
// barrier pair halves the barrier count; always-on causal mask covers the
// padded half-tile when qt is even (overread tile qt+1 <= 31, in-bounds).
__global__ __launch_bounds__(256) void attn_fused(
    const unsigned short* __restrict__ Q, const unsigned short* __restrict__ Kg,
    const unsigned short* __restrict__ Vt, unsigned short* __restrict__ Y) {
  __shared__ __align__(16) unsigned short Ks[128 * 72];
  __shared__ __align__(16) unsigned short Vs[64 * 136];
  __shared__ __align__(16) unsigned short Ps[4][16 * 136];
  int tid = threadIdx.x;
  int wv = tid >> 6, lane = tid & 63, quad = lane >> 4, l15 = lane & 15;
  int l = blockIdx.x;
  int w = l >> 8, c = l & 255;
  int i = c & 31;
  int bh = w * 8 + (c >> 5);
  int qt;
  if (w == 0)      qt = i;
  else if (w == 1) qt = (i + 16) & 31;
  else             qt = (i < 16) ? (30 - 2 * i) : (63 - 2 * i);
  int bbx = bh / H_, hh = bh - bbx * H_;
  int q0 = qt * 64;
  size_t base = (size_t)bh * T_ * D_;
  size_t vbase = (size_t)bh * D_ * T_;
  int qrow = q0 + wv * 16 + l15;
  s16x8 qf0 = *(const s16x8*)&Q[base + (size_t)qrow * D_ + quad * 8];
  s16x8 qf1 = *(const s16x8*)&Q[base + (size_t)qrow * D_ + 32 + quad * 8];
  float lsum[4];
  fx4 oacc[4];
#pragma unroll
  for (int t = 0; t < 4; ++t) {
    lsum[t] = 0.f;
    oacc[t] = fx4{0.f, 0.f, 0.f, 0.f};
  }
  int nDbl = (qt >> 1) + 1;
  int r0s = tid >> 3;          // 0..31
  int c8 = (tid & 7) * 8;      // 0..56
  uint4 ka0, ka1, ka2, ka3, va0, va1, va2, va3;
  {
    const unsigned short* Kp = Kg + base;
    ka0 = *(const uint4*)&Kp[(size_t)r0s * D_ + c8];
    ka1 = *(const uint4*)&Kp[(size_t)(r0s + 32) * D_ + c8];
    ka2 = *(const uint4*)&Kp[(size_t)(r0s + 64) * D_ + c8];
    ka3 = *(const uint4*)&Kp[(size_t)(r0s + 96) * D_ + c8];
    const unsigned short* Vp = Vt + vbase;
    va0 = *(const uint4*)&Vp[(size_t)r0s * T_ + c8];
    va1 = *(const uint4*)&Vp[(size_t)r0s * T_ + 64 + c8];
    va2 = *(const uint4*)&Vp[(size_t)(r0s + 32) * T_ + c8];
    va3 = *(const uint4*)&Vp[(size_t)(r0s + 32) * T_ + 64 + c8];
  }
  unsigned short* pw = &Ps[wv][0];
  for (int kb = 0; kb < nDbl; ++kb) {
    int k0 = kb * 128;
    __syncthreads();
    *(uint4*)&Ks[r0s * 72 + c8] = ka0;
    *(uint4*)&Ks[(r0s + 32) * 72 + c8] = ka1;
    *(uint4*)&Ks[(r0s + 64) * 72 + c8] = ka2;
    *(uint4*)&Ks[(r0s + 96) * 72 + c8] = ka3;
    *(uint4*)&Vs[r0s * 136 + c8] = va0;
    *(uint4*)&Vs[r0s * 136 + 64 + c8] = va1;
    *(uint4*)&Vs[(r0s + 32) * 136 + c8] = va2;
    *(uint4*)&Vs[(r0s + 32) * 136 + 64 + c8] = va3;
    __syncthreads();
    if (kb + 1 < nDbl) {
      int kn = k0 + 128;
      const unsigned short* Kp = Kg + base + (size_t)kn * D_;
      ka0 = *(const uint4*)&Kp[(size_t)r0s * D_ + c8];
      ka1 = *(const uint4*)&Kp[(size_t)(r0s + 32) * D_ + c8];
      ka2 = *(const uint4*)&Kp[(size_t)(r0s + 64) * D_ + c8];
      ka3 = *(const uint4*)&Kp[(size_t)(r0s + 96) * D_ + c8];
      const unsigned short* Vp = Vt + vbase + kn;
      va0 = *(const uint4*)&Vp[(size_t)r0s * T_ + c8];
      va1 = *(const uint4*)&Vp[(size_t)r0s * T_ + 64 + c8];
      va2 = *(const uint4*)&Vp[(size_t)(r0s + 32) * T_ + c8];
      va3 = *(const uint4*)&Vp[(size_t)(r0s + 32) * T_ + 64 + c8];
    }
    fx4 sc[8];
#pragma unroll
    for (int nt = 0; nt < 8; ++nt) {
      sc[nt] = fx4{0.f, 0.f, 0.f, 0.f};
      s16x8 kf0 = *(const s16x8*)&Ks[(nt * 16 + l15) * 72 + quad * 8];
      s16x8 kf1 = *(const s16x8*)&Ks[(nt * 16 + l15) * 72 + 32 + quad * 8];
      sc[nt] = __builtin_amdgcn_mfma_f32_16x16x32_bf16(qf0, kf0, sc[nt], 0, 0, 0);
      sc[nt] = __builtin_amdgcn_mfma_f32_16x16x32_bf16(qf1, kf1, sc[nt], 0, 0, 0);
    }
#pragma unroll
    for (int nt = 0; nt < 8; ++nt)
#pragma unroll
      for (int r = 0; r < 4; ++r) {
        int key = k0 + nt * 16 + l15;
        int row = q0 + wv * 16 + quad * 4 + r;
        float p = (key > row) ? 0.f : __expf(sc[nt][r] * 0.125f);
        lsum[r] += p;
        pw[(quad * 4 + r) * 136 + nt * 16 + l15] = f2bf_trunc(p);
      }
    s16x8 pa[4];
#pragma unroll
    for (int ch = 0; ch < 4; ++ch)
      pa[ch] = *(const s16x8*)&pw[l15 * 136 + ch * 32 + quad * 8];
#pragma unroll
    for (int nt = 0; nt < 4; ++nt) {
#pragma unroll
      for (int ch = 0; ch < 4; ++ch) {
        s16x8 vf = *(const s16x8*)&Vs[(nt * 16 + l15) * 136 + ch * 32 + quad * 8];
        oacc[nt] = __builtin_amdgcn_mfma_f32_16x16x32_bf16(pa[ch], vf, oacc[nt], 0, 0, 0);
      }
    }
  }
#pragma unroll
  for (int r = 0; r < 4; ++r) {
#pragma unroll
    for (int off = 1; off < 16; off <<= 1) lsum[r] += __shfl_xor(lsum[r], off);
  }
#pragma unroll
  for (int nt = 0; nt < 4; ++nt)
#pragma unroll
    for (int r = 0; r < 4; ++r) {
      float o = oacc[nt][r] / lsum[r];
      int token = bbx * T_ + q0 + wv * 16 + quad * 4 + r;
      Y[(size_t)token * C_ + hh * D_ + nt * 16 + l15] = f2bf(o);
    }
}

// ---------------- launcher --------------------------------------------------
extern "C" void kernel_launch(void* const* d_in, const int* in_sizes, int n_in,
                              void* d_out, int out_size, void* d_ws, size_t ws_size,
                              hipStream_t stream) {
  const float* x      = (const float*)d_in[0];
  const float* ln1g   = (const float*)d_in[1];
  const float* ln1b   = (const float*)d_in[2];
  const float* Wattn  = (const float*)d_in[3];
  const float* battn  = (const float*)d_in[4];
  const float* Wcproj = (const float*)d_in[5];
  const float* bcproj = (const float*)d_in[6];
  const float* ln2g   = (const float*)d_in[7];
  const float* ln2b   = (const float*)d_in[8];
  const float* Wfc    = (const float*)d_in[9];
  const float* bfc    = (const float*)d_in[10];
  const float* Wmproj = (const float*)d_in[11];
  const float* bmproj = (const float*)d_in[12];
  float* out = (float*)d_out;
  char* ws = (char*)d_ws;

  unsigned short* WattnT  = (unsigned short*)(ws + 0);          // 2304x768 bf16
  unsigned short* WcprojT = (unsigned short*)(ws + 3538944);    // 768x768
  unsigned short* WfcT    = (unsigned short*)(ws + 4718592);    // 3072x768
  unsigned short* WmprojT = (unsigned short*)(ws + 9437184);    // 768x3072
  unsigned short* hbuf    = (unsigned short*)(ws + 14155776);   // 4096x768 bf16
  unsigned short* Qb      = (unsigned short*)(ws + 20447232);   // [24,2048,64]
  unsigned short* Kb      = (unsigned short*)(ws + 26738688);   // [24,2048,64]
  unsigned short* Vtb     = (unsigned short*)(ws + 33030144);   // [24,64,2048]
  unsigned short* Yb      = (unsigned short*)(ws + 39321600);   // 4096x768 bf16
  float*          x1      = (float*)(ws + 45613056);            // 4096x768 fp32
  unsigned short* Ab      = (unsigned short*)(ws + 58195968);   // 4096x3072 bf16
  // split-K partials overlay Qb..Yb (dead after cproj): 2 x 4096x768 fp32
  float*          Pbuf    = (float*)(ws + 20447232);

  prep<<<11008, 256, 0, stream>>>(Wattn, Wcproj, Wfc, Wmproj,
                                  WattnT, WcprojT, WfcT, WmprojT,
                                  x, ln1g, ln1b, hbuf);

  // qkv: BM=128 BN=96 BK=32 -> 768 blocks, 28KB LDS => 3/CU fully resident
  gemm_db<128, 96, 32, 0><<<dim3(24, 32), 256, 0, stream>>>(
      hbuf, WattnT, battn, nullptr, nullptr, nullptr, Qb, Kb, Vtb,
      4096, 2304, 768, 768);

  attn_fused<<<768, 256, 0, stream>>>(Qb, Kb, Vtb, Yb);

  // cproj: BM=128 BN=64 BK=64 swizzled, 384 blocks
  gemm_db<128, 64, 64, 1><<<dim3(32, 12), 256, 0, stream>>>(
      Yb, WcprojT, bcproj, x, x1, nullptr, nullptr, nullptr, nullptr,
      4096, 768, 768, 768);

  layernorm_bf16<<<4096, 256, 0, stream>>>(x1, ln2g, ln2b, hbuf);

  // fc: BM=128 BN=128 BK=32, tanh-gelu epilogue
  gemm_db<128, 128, 32, 2><<<dim3(24, 32), 256, 0, stream>>>(
      hbuf, WfcT, bfc, nullptr, nullptr, Ab, nullptr, nullptr, nullptr,
      4096, 3072, 768, 768);

  // mproj split-K=2: 768 blocks = 3/CU resident uniform, K chunks of 1536
  gemm_db<128, 64, 64, 3><<<dim3(32, 12, 2), 256, 0, stream>>>(
      Ab, WmprojT, bmproj, nullptr, Pbuf, nullptr, nullptr, nullptr, nullptr,
      4096, 768, 3072, 1536);

  // out = x1 + P0 + P1 + bias  (786432 float4 / 256 per block = 3072 blocks)
  reduce_out<<<3072, 256, 0, stream>>>(x1, Pbuf, bmproj, out);
}

// Round 13
// 259.874 us; speedup vs baseline: 1.0220x; 1.0195x over previous
//
#include <hip/hip_runtime.h>
#include <cstdint>
#include <cstddef>

#define B_ 2
#define T_ 2048
#define C_ 768
#define H_ 12
#define D_ 64

typedef __attribute__((ext_vector_type(8))) short s16x8;
typedef __attribute__((ext_vector_type(4))) float fx4;

static __device__ __forceinline__ unsigned short f2bf(float f) {
  unsigned u = __builtin_bit_cast(unsigned, f);
  unsigned r = u + 0x7fffu + ((u >> 16) & 1u);
  return (unsigned short)(r >> 16);
}
static __device__ __forceinline__ unsigned short f2bf_trunc(float f) {
  return (unsigned short)(__builtin_bit_cast(unsigned, f) >> 16);
}

static __device__ __forceinline__ void glds16(const unsigned short* g, unsigned short* l) {
  __builtin_amdgcn_global_load_lds(
      (const __attribute__((address_space(1))) void*)(g),
      (__attribute__((address_space(3))) void*)(l), 16, 0, 0);
}

// ---------------- fused prep: 4 weight transposes + LN1 in one launch -------
__global__ __launch_bounds__(256) void prep(
    const float* __restrict__ Wattn, const float* __restrict__ Wcproj,
    const float* __restrict__ Wfc, const float* __restrict__ Wmproj,
    unsigned short* __restrict__ WattnT, unsigned short* __restrict__ WcprojT,
    unsigned short* __restrict__ WfcT, unsigned short* __restrict__ WmprojT,
    const float* __restrict__ X, const float* __restrict__ g,
    const float* __restrict__ bb, unsigned short* __restrict__ O) {
  __shared__ float tile[32][33];
  __shared__ float ps[8];
  int bid = blockIdx.x, tid = threadIdx.x;
  if (bid < 6912) {
    const float* W; unsigned short* Wt; int R, C, idx;
    if (bid < 1728)      { W = Wattn;  Wt = WattnT;  R = 768;  C = 2304; idx = bid; }
    else if (bid < 2304) { W = Wcproj; Wt = WcprojT; R = 768;  C = 768;  idx = bid - 1728; }
    else if (bid < 4608) { W = Wfc;    Wt = WfcT;    R = 768;  C = 3072; idx = bid - 2304; }
    else                 { W = Wmproj; Wt = WmprojT; R = 3072; C = 768;  idx = bid - 4608; }
    int ct = C >> 5;
    int c0 = (idx % ct) * 32, r0 = (idx / ct) * 32;
    int tx = tid & 31, ty = tid >> 5;
#pragma unroll
    for (int i = 0; i < 4; ++i)
      tile[ty + i * 8][tx] = W[(size_t)(r0 + ty + i * 8) * C + (c0 + tx)];
    __syncthreads();
#pragma unroll
    for (int i = 0; i < 4; ++i)
      Wt[(size_t)(c0 + ty + i * 8) * R + (r0 + tx)] = f2bf(tile[tx][ty + i * 8]);
  } else {
    int row = bid - 6912;
    const float* xr = X + (size_t)row * C_;
    float v0 = xr[tid], v1 = xr[tid + 256], v2 = xr[tid + 512];
    float s = v0 + v1 + v2;
    float s2 = v0 * v0 + v1 * v1 + v2 * v2;
#pragma unroll
    for (int off = 1; off < 64; off <<= 1) {
      s += __shfl_xor(s, off);
      s2 += __shfl_xor(s2, off);
    }
    int wv = tid >> 6;
    if ((tid & 63) == 0) { ps[wv] = s; ps[wv + 4] = s2; }
    __syncthreads();
    s = ps[0] + ps[1] + ps[2] + ps[3];
    s2 = ps[4] + ps[5] + ps[6] + ps[7];
    float mu = s * (1.f / C_);
    float var = s2 * (1.f / C_) - mu * mu;
    float rstd = rsqrtf(var + 1e-5f);
    unsigned short* orow = O + (size_t)row * C_;
    orow[tid]       = f2bf((v0 - mu) * rstd * g[tid]       + bb[tid]);
    orow[tid + 256] = f2bf((v1 - mu) * rstd * g[tid + 256] + bb[tid + 256]);
    orow[tid + 512] = f2bf((v2 - mu) * rstd * g[tid + 512] + bb[tid + 512]);
  }
}

// ---------------- layernorm fp32 -> bf16 ------------------------------------
__global__ __launch_bounds__(256) void layernorm_bf16(
    const float* __restrict__ X, const float* __restrict__ g,
    const float* __restrict__ bb, unsigned short* __restrict__ O) {
  int row = blockIdx.x, tid = threadIdx.x;
  const float* xr = X + (size_t)row * C_;
  float v0 = xr[tid], v1 = xr[tid + 256], v2 = xr[tid + 512];
  float s = v0 + v1 + v2;
  float s2 = v0 * v0 + v1 * v1 + v2 * v2;
#pragma unroll
  for (int off = 1; off < 64; off <<= 1) {
    s += __shfl_xor(s, off);
    s2 += __shfl_xor(s2, off);
  }
  __shared__ float ps[8];
  int wv = tid >> 6;
  if ((tid & 63) == 0) { ps[wv] = s; ps[wv + 4] = s2; }
  __syncthreads();
  s = ps[0] + ps[1] + ps[2] + ps[3];
  s2 = ps[4] + ps[5] + ps[6] + ps[7];
  float mu = s * (1.f / C_);
  float var = s2 * (1.f / C_) - mu * mu;
  float rstd = rsqrtf(var + 1e-5f);
  unsigned short* orow = O + (size_t)row * C_;
  orow[tid]       = f2bf((v0 - mu) * rstd * g[tid]       + bb[tid]);
  orow[tid + 256] = f2bf((v1 - mu) * rstd * g[tid + 256] + bb[tid + 256]);
  orow[tid + 512] = f2bf((v2 - mu) * rstd * g[tid + 512] + bb[tid + 512]);
}

// ---------------- reduce: out = x1 + P0 + P1 + bias (float4) ----------------
// one float4 per thread; 4096*768 fp32 = 786432 float4 -> grid 3072 x 256
__global__ __launch_bounds__(256) void reduce_out(
    const float* __restrict__ x1, const float* __restrict__ P,
    const float* __restrict__ bias, float* __restrict__ out) {
  int idx = blockIdx.x * 256 + threadIdx.x;
  float4 a = ((const float4*)x1)[idx];
  float4 p = ((const float4*)P)[idx];
  float4 q = ((const float4*)(P + (size_t)4096 * 768))[idx];
  float4 b = ((const float4*)bias)[idx % 192];
  float4 o;
  o.x = a.x + p.x + q.x + b.x;
  o.y = a.y + p.y + q.y + b.y;
  o.z = a.z + p.z + q.z + b.z;
  o.w = a.w + p.w + q.w + b.w;
  ((float4*)out)[idx] = o;
}

// ---------------- double-buffered GEMM: C = A[M,K-chunk] * Bt^T + bias ------
// 256 threads = 4 waves (2x2); glds width-16 staging; LDS double buffer.
// BK==64: XOR-swizzle chunk ^ (row&7) (verified 0-conflict + faster, r5/r7).
// BK==32: no swizzle (r11/r12: fixing the 8-way conflict is a net loss).
// Epilogue (MODEs 1/2/3): nt-innermost store order so each wave emits a
// contiguous 128B(bf16)/256B(fp32) span per m-row -> L2 merges full lines,
// avoiding write-allocate RMW fetch (r12: fc FETCH 30MB vs 11MB of inputs).
// MODE 0: QKV scatter; MODE 1: resid+bias fp32 (m-fastest grid);
// MODE 2: erf-gelu bf16; MODE 3: raw fp32 partial to outF + z*M*N.
template <int BM, int BN, int BK, int MODE>
__global__ __launch_bounds__(256) void gemm_db(
    const unsigned short* __restrict__ A, const unsigned short* __restrict__ Bt,
    const float* __restrict__ bias, const float* __restrict__ resid,
    float* __restrict__ outF, unsigned short* __restrict__ outB,
    unsigned short* __restrict__ qO, unsigned short* __restrict__ kO,
    unsigned short* __restrict__ vtO, int M, int N, int K, int KC) {
  constexpr int AT = BM / 32;
  constexpr int BT = BN / 32;
  constexpr int KS = BK / 32;
  constexpr int ACH = BM * BK / 8;
  constexpr int BCH = BN * BK / 8;
  constexpr int ASZ = BM * BK, BSZ = BN * BK;
  constexpr bool SWIZ = (BK == 64);
  __shared__ __align__(16) unsigned short As[2 * ASZ];
  __shared__ __align__(16) unsigned short Bs[2 * BSZ];
  int tid = threadIdx.x;
  int wv = tid >> 6, lane = tid & 63, quad = lane >> 4, l15 = lane & 15;
  int wm = wv >> 1, wn = wv & 1;
  int m0, n0;
  if (MODE == 1 || MODE == 3) { m0 = blockIdx.x * BM; n0 = blockIdx.y * BN; }
  else                        { n0 = blockIdx.x * BN; m0 = blockIdx.y * BM; }
  const unsigned short* Ak = A + (size_t)blockIdx.z * KC;
  const unsigned short* Bk = Bt + (size_t)blockIdx.z * KC;
  fx4 acc[AT][BT];
#pragma unroll
  for (int i = 0; i < AT; ++i)
#pragma unroll
    for (int j = 0; j < BT; ++j) acc[i][j] = fx4{0.f, 0.f, 0.f, 0.f};

  int nk = KC / BK;
#pragma unroll
  for (int i0 = 0; i0 < ACH; i0 += 256)
    if (ACH - i0 >= 256 || tid < ACH - i0) {
      int e = (i0 + tid) * 8;
      int row = e / BK, cg = (e & (BK - 1)) >> 3;
      if (SWIZ) cg ^= (row & 7);
      glds16(&Ak[(size_t)(m0 + row) * K + (cg << 3)], &As[(i0 + (tid & ~63)) * 8]);
    }
#pragma unroll
  for (int i0 = 0; i0 < BCH; i0 += 256)
    if (BCH - i0 >= 256 || tid < BCH - i0) {
      int e = (i0 + tid) * 8;
      int row = e / BK, cg = (e & (BK - 1)) >> 3;
      if (SWIZ) cg ^= (row & 7);
      glds16(&Bk[(size_t)(n0 + row) * K + (cg << 3)], &Bs[(i0 + (tid & ~63)) * 8]);
    }
  for (int kt = 0; kt < nk; ++kt) {
    int cur = kt & 1;
    __syncthreads();
    if (kt + 1 < nk) {
      int kb = (kt + 1) * BK;
      int nxt = cur ^ 1;
#pragma unroll
      for (int i0 = 0; i0 < ACH; i0 += 256)
        if (ACH - i0 >= 256 || tid < ACH - i0) {
          int e = (i0 + tid) * 8;
          int row = e / BK, cg = (e & (BK - 1)) >> 3;
          if (SWIZ) cg ^= (row & 7);
          glds16(&Ak[(size_t)(m0 + row) * K + kb + (cg << 3)],
                 &As[nxt * ASZ + (i0 + (tid & ~63)) * 8]);
        }
#pragma unroll
      for (int i0 = 0; i0 < BCH; i0 += 256)
        if (BCH - i0 >= 256 || tid < BCH - i0) {
          int e = (i0 + tid) * 8;
          int row = e / BK, cg = (e & (BK - 1)) >> 3;
          if (SWIZ) cg ^= (row & 7);
          glds16(&Bk[(size_t)(n0 + row) * K + kb + (cg << 3)],
                 &Bs[nxt * BSZ + (i0 + (tid & ~63)) * 8]);
        }
    }
#pragma unroll
    for (int ks = 0; ks < KS; ++ks) {
      s16x8 af[AT], bf[BT];
#pragma unroll
      for (int mt = 0; mt < AT; ++mt) {
        int r = wm * (BM / 2) + mt * 16 + l15;
        int cg = (ks * 32 + quad * 8) >> 3;
        if (SWIZ) cg ^= (r & 7);
        af[mt] = *(const s16x8*)&As[cur * ASZ + r * BK + (cg << 3)];
      }
#pragma unroll
      for (int nt = 0; nt < BT; ++nt) {
        int r = wn * (BN / 2) + nt * 16 + l15;
        int cg = (ks * 32 + quad * 8) >> 3;
        if (SWIZ) cg ^= (r & 7);
        bf[nt] = *(const s16x8*)&Bs[cur * BSZ + r * BK + (cg << 3)];
      }
#pragma unroll
      for (int mt = 0; mt < AT; ++mt)
#pragma unroll
        for (int nt = 0; nt < BT; ++nt)
          acc[mt][nt] = __builtin_amdgcn_mfma_f32_16x16x32_bf16(af[mt], bf[nt], acc[mt][nt], 0, 0, 0);
    }
  }

  if (MODE == 0) {
#pragma unroll
    for (int mt = 0; mt < AT; ++mt)
#pragma unroll
      for (int nt = 0; nt < BT; ++nt) {
        int mb = m0 + wm * (BM / 2) + mt * 16 + quad * 4;
        int n = n0 + wn * (BN / 2) + nt * 16 + l15;
        int which = n / C_;
        int within = n - which * C_;
        int hd = within >> 6, d = within & 63;
        int bbx = mb >> 11, t = mb & 2047;
        size_t bh = (size_t)(bbx * H_ + hd);
        float b = bias[n];
        if (which == 2) {
          unsigned v01 = (unsigned)f2bf(acc[mt][nt][0] + b) |
                         ((unsigned)f2bf(acc[mt][nt][1] + b) << 16);
          unsigned v23 = (unsigned)f2bf(acc[mt][nt][2] + b) |
                         ((unsigned)f2bf(acc[mt][nt][3] + b) << 16);
          *(uint2*)&vtO[(bh * D_ + d) * T_ + t] = uint2{v01, v23};
        } else {
          unsigned short* dst = (which == 0) ? qO : kO;
#pragma unroll
          for (int r = 0; r < 4; ++r)
            dst[(bh * T_ + t + r) * D_ + d] = f2bf(acc[mt][nt][r] + b);
        }
      }
  } else {
    // nt-innermost: per m-row, the wave's 4(BT) stores span contiguous lines
#pragma unroll
    for (int mt = 0; mt < AT; ++mt) {
      int mb = m0 + wm * (BM / 2) + mt * 16 + quad * 4;
#pragma unroll
      for (int r = 0; r < 4; ++r) {
        int m = mb + r;
#pragma unroll
        for (int nt = 0; nt < BT; ++nt) {
          int n = n0 + wn * (BN / 2) + nt * 16 + l15;
          if (MODE == 1) {
            float v = acc[mt][nt][r] + bias[n];
            outF[(size_t)m * N + n] = resid[(size_t)m * N + n] + v;
          } else if (MODE == 3) {
            float* P = outF + (size_t)blockIdx.z * M * N;
            P[(size_t)m * N + n] = acc[mt][nt][r];
          } else {
            float v = acc[mt][nt][r] + bias[n];
            float gl = 0.5f * v * (1.f + erff(v * 0.70710678118654752f));
            outB[(size_t)m * N + n] = f2bf(gl);
          }
        }
      }
    }
  }
}

// ---------------- fused causal flash attention (128-key iterations) ---------
// LDS-staged K/V, register prefetch, balanced qt schedule (r7). 128 keys per
// barrier pair halves the barrier count; always-on causal mask covers the
// padded half-tile when qt is even (overread tile qt+1 <= 31, in-bounds).
__global__ __launch_bounds__(256) void attn_fused(
    const unsigned short* __restrict__ Q, const unsigned short* __restrict__ Kg,
    const unsigned short* __restrict__ Vt, unsigned short* __restrict__ Y) {
  __shared__ __align__(16) unsigned short Ks[128 * 72];
  __shared__ __align__(16) unsigned short Vs[64 * 136];
  __shared__ __align__(16) unsigned short Ps[4][16 * 136];
  int tid = threadIdx.x;
  int wv = tid >> 6, lane = tid & 63, quad = lane >> 4, l15 = lane & 15;
  int l = blockIdx.x;
  int w = l >> 8, c = l & 255;
  int i = c & 31;
  int bh = w * 8 + (c >> 5);
  int qt;
  if (w == 0)      qt = i;
  else if (w == 1) qt = (i + 16) & 31;
  else             qt = (i < 16) ? (30 - 2 * i) : (63 - 2 * i);
  int bbx = bh / H_, hh = bh - bbx * H_;
  int q0 = qt * 64;
  size_t base = (size_t)bh * T_ * D_;
  size_t vbase = (size_t)bh * D_ * T_;
  int qrow = q0 + wv * 16 + l15;
  s16x8 qf0 = *(const s16x8*)&Q[base + (size_t)qrow * D_ + quad * 8];
  s16x8 qf1 = *(const s16x8*)&Q[base + (size_t)qrow * D_ + 32 + quad * 8];
  float lsum[4];
  fx4 oacc[4];
#pragma unroll
  for (int t = 0; t < 4; ++t) {
    lsum[t] = 0.f;
    oacc[t] = fx4{0.f, 0.f, 0.f, 0.f};
  }
  int nDbl = (qt >> 1) + 1;
  int r0s = tid >> 3;          // 0..31
  int c8 = (tid & 7) * 8;      // 0..56
  uint4 ka0, ka1, ka2, ka3, va0, va1, va2, va3;
  {
    const unsigned short* Kp = Kg + base;
    ka0 = *(const uint4*)&Kp[(size_t)r0s * D_ + c8];
    ka1 = *(const uint4*)&Kp[(size_t)(r0s + 32) * D_ + c8];
    ka2 = *(const uint4*)&Kp[(size_t)(r0s + 64) * D_ + c8];
    ka3 = *(const uint4*)&Kp[(size_t)(r0s + 96) * D_ + c8];
    const unsigned short* Vp = Vt + vbase;
    va0 = *(const uint4*)&Vp[(size_t)r0s * T_ + c8];
    va1 = *(const uint4*)&Vp[(size_t)r0s * T_ + 64 + c8];
    va2 = *(const uint4*)&Vp[(size_t)(r0s + 32) * T_ + c8];
    va3 = *(const uint4*)&Vp[(size_t)(r0s + 32) * T_ + 64 + c8];
  }
  unsigned short* pw = &Ps[wv][0];
  for (int kb = 0; kb < nDbl; ++kb) {
    int k0 = kb * 128;
    __syncthreads();
    *(uint4*)&Ks[r0s * 72 + c8] = ka0;
    *(uint4*)&Ks[(r0s + 32) * 72 + c8] = ka1;
    *(uint4*)&Ks[(r0s + 64) * 72 + c8] = ka2;
    *(uint4*)&Ks[(r0s + 96) * 72 + c8] = ka3;
    *(uint4*)&Vs[r0s * 136 + c8] = va0;
    *(uint4*)&Vs[r0s * 136 + 64 + c8] = va1;
    *(uint4*)&Vs[(r0s + 32) * 136 + c8] = va2;
    *(uint4*)&Vs[(r0s + 32) * 136 + 64 + c8] = va3;
    __syncthreads();
    if (kb + 1 < nDbl) {
      int kn = k0 + 128;
      const unsigned short* Kp = Kg + base + (size_t)kn * D_;
      ka0 = *(const uint4*)&Kp[(size_t)r0s * D_ + c8];
      ka1 = *(const uint4*)&Kp[(size_t)(r0s + 32) * D_ + c8];
      ka2 = *(const uint4*)&Kp[(size_t)(r0s + 64) * D_ + c8];
      ka3 = *(const uint4*)&Kp[(size_t)(r0s + 96) * D_ + c8];
      const unsigned short* Vp = Vt + vbase + kn;
      va0 = *(const uint4*)&Vp[(size_t)r0s * T_ + c8];
      va1 = *(const uint4*)&Vp[(size_t)r0s * T_ + 64 + c8];
      va2 = *(const uint4*)&Vp[(size_t)(r0s + 32) * T_ + c8];
      va3 = *(const uint4*)&Vp[(size_t)(r0s + 32) * T_ + 64 + c8];
    }
    fx4 sc[8];
#pragma unroll
    for (int nt = 0; nt < 8; ++nt) {
      sc[nt] = fx4{0.f, 0.f, 0.f, 0.f};
      s16x8 kf0 = *(const s16x8*)&Ks[(nt * 16 + l15) * 72 + quad * 8];
      s16x8 kf1 = *(const s16x8*)&Ks[(nt * 16 + l15) * 72 + 32 + quad * 8];
      sc[nt] = __builtin_amdgcn_mfma_f32_16x16x32_bf16(qf0, kf0, sc[nt], 0, 0, 0);
      sc[nt] = __builtin_amdgcn_mfma_f32_16x16x32_bf16(qf1, kf1, sc[nt], 0, 0, 0);
    }
#pragma unroll
    for (int nt = 0; nt < 8; ++nt)
#pragma unroll
      for (int r = 0; r < 4; ++r) {
        int key = k0 + nt * 16 + l15;
        int row = q0 + wv * 16 + quad * 4 + r;
        float p = (key > row) ? 0.f : __expf(sc[nt][r] * 0.125f);
        lsum[r] += p;
        pw[(quad * 4 + r) * 136 + nt * 16 + l15] = f2bf_trunc(p);
      }
    s16x8 pa[4];
#pragma unroll
    for (int ch = 0; ch < 4; ++ch)
      pa[ch] = *(const s16x8*)&pw[l15 * 136 + ch * 32 + quad * 8];
#pragma unroll
    for (int nt = 0; nt < 4; ++nt) {
#pragma unroll
      for (int ch = 0; ch < 4; ++ch) {
        s16x8 vf = *(const s16x8*)&Vs[(nt * 16 + l15) * 136 + ch * 32 + quad * 8];
        oacc[nt] = __builtin_amdgcn_mfma_f32_16x16x32_bf16(pa[ch], vf, oacc[nt], 0, 0, 0);
      }
    }
  }
#pragma unroll
  for (int r = 0; r < 4; ++r) {
#pragma unroll
    for (int off = 1; off < 16; off <<= 1) lsum[r] += __shfl_xor(lsum[r], off);
  }
#pragma unroll
  for (int nt = 0; nt < 4; ++nt)
#pragma unroll
    for (int r = 0; r < 4; ++r) {
      float o = oacc[nt][r] / lsum[r];
      int token = bbx * T_ + q0 + wv * 16 + quad * 4 + r;
      Y[(size_t)token * C_ + hh * D_ + nt * 16 + l15] = f2bf(o);
    }
}

// ---------------- launcher --------------------------------------------------
extern "C" void kernel_launch(void* const* d_in, const int* in_sizes, int n_in,
                              void* d_out, int out_size, void* d_ws, size_t ws_size,
                              hipStream_t stream) {
  const float* x      = (const float*)d_in[0];
  const float* ln1g   = (const float*)d_in[1];
  const float* ln1b   = (const float*)d_in[2];
  const float* Wattn  = (const float*)d_in[3];
  const float* battn  = (const float*)d_in[4];
  const float* Wcproj = (const float*)d_in[5];
  const float* bcproj = (const float*)d_in[6];
  const float* ln2g   = (const float*)d_in[7];
  const float* ln2b   = (const float*)d_in[8];
  const float* Wfc    = (const float*)d_in[9];
  const float* bfc    = (const float*)d_in[10];
  const float* Wmproj = (const float*)d_in[11];
  const float* bmproj = (const float*)d_in[12];
  float* out = (float*)d_out;
  char* ws = (char*)d_ws;

  unsigned short* WattnT  = (unsigned short*)(ws + 0);          // 2304x768 bf16
  unsigned short* WcprojT = (unsigned short*)(ws + 3538944);    // 768x768
  unsigned short* WfcT    = (unsigned short*)(ws + 4718592);    // 3072x768
  unsigned short* WmprojT = (unsigned short*)(ws + 9437184);    // 768x3072
  unsigned short* hbuf    = (unsigned short*)(ws + 14155776);   // 4096x768 bf16
  unsigned short* Qb      = (unsigned short*)(ws + 20447232);   // [24,2048,64]
  unsigned short* Kb      = (unsigned short*)(ws + 26738688);   // [24,2048,64]
  unsigned short* Vtb     = (unsigned short*)(ws + 33030144);   // [24,64,2048]
  unsigned short* Yb      = (unsigned short*)(ws + 39321600);   // 4096x768 bf16
  float*          x1      = (float*)(ws + 45613056);            // 4096x768 fp32
  unsigned short* Ab      = (unsigned short*)(ws + 58195968);   // 4096x3072 bf16
  // split-K partials overlay Qb..Yb (dead after cproj): 2 x 4096x768 fp32
  float*          Pbuf    = (float*)(ws + 20447232);

  prep<<<11008, 256, 0, stream>>>(Wattn, Wcproj, Wfc, Wmproj,
                                  WattnT, WcprojT, WfcT, WmprojT,
                                  x, ln1g, ln1b, hbuf);

  // qkv: BM=128 BN=96 BK=32 -> 768 blocks, 28KB LDS => 3/CU fully resident
  gemm_db<128, 96, 32, 0><<<dim3(24, 32), 256, 0, stream>>>(
      hbuf, WattnT, battn, nullptr, nullptr, nullptr, Qb, Kb, Vtb,
      4096, 2304, 768, 768);

  attn_fused<<<768, 256, 0, stream>>>(Qb, Kb, Vtb, Yb);

  // cproj: BM=128 BN=64 BK=64 swizzled, 384 blocks
  gemm_db<128, 64, 64, 1><<<dim3(32, 12), 256, 0, stream>>>(
      Yb, WcprojT, bcproj, x, x1, nullptr, nullptr, nullptr, nullptr,
      4096, 768, 768, 768);

  layernorm_bf16<<<4096, 256, 0, stream>>>(x1, ln2g, ln2b, hbuf);

  // fc: BM=128 BN=128 BK=32, erf-gelu epilogue (r10-measured best)
  gemm_db<128, 128, 32, 2><<<dim3(24, 32), 256, 0, stream>>>(
      hbuf, WfcT, bfc, nullptr, nullptr, Ab, nullptr, nullptr, nullptr,
      4096, 3072, 768, 768);

  // mproj split-K=2: 768 blocks = 3/CU resident uniform, K chunks of 1536
  gemm_db<128, 64, 64, 3><<<dim3(32, 12, 2), 256, 0, stream>>>(
      Ab, WmprojT, bmproj, nullptr, Pbuf, nullptr, nullptr, nullptr, nullptr,
      4096, 768, 3072, 1536);

  // out = x1 + P0 + P1 + bias  (786432 float4 / 256 per block = 3072 blocks)
  reduce_out<<<3072, 256, 0, stream>>>(x1, Pbuf, bmproj, out);
}

// Round 14
// 254.673 us; speedup vs baseline: 1.0429x; 1.0204x over previous
//
#include <hip/hip_runtime.h>
#include <cstdint>
#include <cstddef>

#define B_ 2
#define T_ 2048
#define C_ 768
#define H_ 12
#define D_ 64

typedef __attribute__((ext_vector_type(8))) short s16x8;
typedef __attribute__((ext_vector_type(4))) float fx4;

static __device__ __forceinline__ unsigned short f2bf(float f) {
  unsigned u = __builtin_bit_cast(unsigned, f);
  unsigned r = u + 0x7fffu + ((u >> 16) & 1u);
  return (unsigned short)(r >> 16);
}
static __device__ __forceinline__ unsigned short f2bf_trunc(float f) {
  return (unsigned short)(__builtin_bit_cast(unsigned, f) >> 16);
}

static __device__ __forceinline__ void glds16(const unsigned short* g, unsigned short* l) {
  __builtin_amdgcn_global_load_lds(
      (const __attribute__((address_space(1))) void*)(g),
      (__attribute__((address_space(3))) void*)(l), 16, 0, 0);
}

// ---------------- fused prep: 4 weight transposes + LN1 in one launch -------
__global__ __launch_bounds__(256) void prep(
    const float* __restrict__ Wattn, const float* __restrict__ Wcproj,
    const float* __restrict__ Wfc, const float* __restrict__ Wmproj,
    unsigned short* __restrict__ WattnT, unsigned short* __restrict__ WcprojT,
    unsigned short* __restrict__ WfcT, unsigned short* __restrict__ WmprojT,
    const float* __restrict__ X, const float* __restrict__ g,
    const float* __restrict__ bb, unsigned short* __restrict__ O) {
  __shared__ float tile[32][33];
  __shared__ float ps[8];
  int bid = blockIdx.x, tid = threadIdx.x;
  if (bid < 6912) {
    const float* W; unsigned short* Wt; int R, C, idx;
    if (bid < 1728)      { W = Wattn;  Wt = WattnT;  R = 768;  C = 2304; idx = bid; }
    else if (bid < 2304) { W = Wcproj; Wt = WcprojT; R = 768;  C = 768;  idx = bid - 1728; }
    else if (bid < 4608) { W = Wfc;    Wt = WfcT;    R = 768;  C = 3072; idx = bid - 2304; }
    else                 { W = Wmproj; Wt = WmprojT; R = 3072; C = 768;  idx = bid - 4608; }
    int ct = C >> 5;
    int c0 = (idx % ct) * 32, r0 = (idx / ct) * 32;
    int tx = tid & 31, ty = tid >> 5;
#pragma unroll
    for (int i = 0; i < 4; ++i)
      tile[ty + i * 8][tx] = W[(size_t)(r0 + ty + i * 8) * C + (c0 + tx)];
    __syncthreads();
#pragma unroll
    for (int i = 0; i < 4; ++i)
      Wt[(size_t)(c0 + ty + i * 8) * R + (r0 + tx)] = f2bf(tile[tx][ty + i * 8]);
  } else {
    int row = bid - 6912;
    const float* xr = X + (size_t)row * C_;
    float v0 = xr[tid], v1 = xr[tid + 256], v2 = xr[tid + 512];
    float s = v0 + v1 + v2;
    float s2 = v0 * v0 + v1 * v1 + v2 * v2;
#pragma unroll
    for (int off = 1; off < 64; off <<= 1) {
      s += __shfl_xor(s, off);
      s2 += __shfl_xor(s2, off);
    }
    int wv = tid >> 6;
    if ((tid & 63) == 0) { ps[wv] = s; ps[wv + 4] = s2; }
    __syncthreads();
    s = ps[0] + ps[1] + ps[2] + ps[3];
    s2 = ps[4] + ps[5] + ps[6] + ps[7];
    float mu = s * (1.f / C_);
    float var = s2 * (1.f / C_) - mu * mu;
    float rstd = rsqrtf(var + 1e-5f);
    unsigned short* orow = O + (size_t)row * C_;
    orow[tid]       = f2bf((v0 - mu) * rstd * g[tid]       + bb[tid]);
    orow[tid + 256] = f2bf((v1 - mu) * rstd * g[tid + 256] + bb[tid + 256]);
    orow[tid + 512] = f2bf((v2 - mu) * rstd * g[tid + 512] + bb[tid + 512]);
  }
}

// ---------------- layernorm fp32 -> bf16 ------------------------------------
__global__ __launch_bounds__(256) void layernorm_bf16(
    const float* __restrict__ X, const float* __restrict__ g,
    const float* __restrict__ bb, unsigned short* __restrict__ O) {
  int row = blockIdx.x, tid = threadIdx.x;
  const float* xr = X + (size_t)row * C_;
  float v0 = xr[tid], v1 = xr[tid + 256], v2 = xr[tid + 512];
  float s = v0 + v1 + v2;
  float s2 = v0 * v0 + v1 * v1 + v2 * v2;
#pragma unroll
  for (int off = 1; off < 64; off <<= 1) {
    s += __shfl_xor(s, off);
    s2 += __shfl_xor(s2, off);
  }
  __shared__ float ps[8];
  int wv = tid >> 6;
  if ((tid & 63) == 0) { ps[wv] = s; ps[wv + 4] = s2; }
  __syncthreads();
  s = ps[0] + ps[1] + ps[2] + ps[3];
  s2 = ps[4] + ps[5] + ps[6] + ps[7];
  float mu = s * (1.f / C_);
  float var = s2 * (1.f / C_) - mu * mu;
  float rstd = rsqrtf(var + 1e-5f);
  unsigned short* orow = O + (size_t)row * C_;
  orow[tid]       = f2bf((v0 - mu) * rstd * g[tid]       + bb[tid]);
  orow[tid + 256] = f2bf((v1 - mu) * rstd * g[tid + 256] + bb[tid + 256]);
  orow[tid + 512] = f2bf((v2 - mu) * rstd * g[tid + 512] + bb[tid + 512]);
}

// ---------------- reduce: out = x1 + P0 + P1 + bias (float4) ----------------
__global__ __launch_bounds__(256) void reduce_out(
    const float* __restrict__ x1, const float* __restrict__ P,
    const float* __restrict__ bias, float* __restrict__ out) {
  int idx = blockIdx.x * 256 + threadIdx.x;
  float4 a = ((const float4*)x1)[idx];
  float4 p = ((const float4*)P)[idx];
  float4 q = ((const float4*)(P + (size_t)4096 * 768))[idx];
  float4 b = ((const float4*)bias)[idx % 192];
  float4 o;
  o.x = a.x + p.x + q.x + b.x;
  o.y = a.y + p.y + q.y + b.y;
  o.z = a.z + p.z + q.z + b.z;
  o.w = a.w + p.w + q.w + b.w;
  ((float4*)out)[idx] = o;
}

// ---------------- double-buffered GEMM, 512 threads = 8 waves (4m x 2n) -----
// Wave tile (BM/4) x (BN/2). At 3 blocks/CU this gives 24 waves/CU (vs 12
// with 4-wave blocks) — r13's per-iter time was 2x the m97 reference at the
// same tile config purely from stall exposure; doubling resident waves is
// the TLP fix. Tiles/LDS/grids unchanged.
// BK==64: XOR-swizzle chunk ^ (row&7) (verified 0-conflict + faster).
// BK==32: no swizzle (r11/r12: net loss).
// MODE 0: QKV scatter; MODE 1: resid+bias fp32 (m-fastest grid);
// MODE 2: erf-gelu bf16; MODE 3: raw fp32 partial to outF + z*M*N.
template <int BM, int BN, int BK, int MODE>
__global__ __launch_bounds__(512) void gemm_db(
    const unsigned short* __restrict__ A, const unsigned short* __restrict__ Bt,
    const float* __restrict__ bias, const float* __restrict__ resid,
    float* __restrict__ outF, unsigned short* __restrict__ outB,
    unsigned short* __restrict__ qO, unsigned short* __restrict__ kO,
    unsigned short* __restrict__ vtO, int M, int N, int K, int KC) {
  constexpr int WM = BM / 4, WN = BN / 2;
  constexpr int AT = WM / 16;
  constexpr int BT = WN / 16;
  constexpr int KS = BK / 32;
  constexpr int ACH = BM * BK / 8;
  constexpr int BCH = BN * BK / 8;
  constexpr int ASZ = BM * BK, BSZ = BN * BK;
  constexpr bool SWIZ = (BK == 64);
  __shared__ __align__(16) unsigned short As[2 * ASZ];
  __shared__ __align__(16) unsigned short Bs[2 * BSZ];
  int tid = threadIdx.x;
  int wv = tid >> 6, lane = tid & 63, quad = lane >> 4, l15 = lane & 15;
  int wm = wv >> 1, wn = wv & 1;
  int m0, n0;
  if (MODE == 1 || MODE == 3) { m0 = blockIdx.x * BM; n0 = blockIdx.y * BN; }
  else                        { n0 = blockIdx.x * BN; m0 = blockIdx.y * BM; }
  const unsigned short* Ak = A + (size_t)blockIdx.z * KC;
  const unsigned short* Bk = Bt + (size_t)blockIdx.z * KC;
  fx4 acc[AT][BT];
#pragma unroll
  for (int i = 0; i < AT; ++i)
#pragma unroll
    for (int j = 0; j < BT; ++j) acc[i][j] = fx4{0.f, 0.f, 0.f, 0.f};

  int nk = KC / BK;
#pragma unroll
  for (int i0 = 0; i0 < ACH; i0 += 512)
    if (ACH - i0 >= 512 || tid < ACH - i0) {
      int e = (i0 + tid) * 8;
      int row = e / BK, cg = (e & (BK - 1)) >> 3;
      if (SWIZ) cg ^= (row & 7);
      glds16(&Ak[(size_t)(m0 + row) * K + (cg << 3)], &As[(i0 + (tid & ~63)) * 8]);
    }
#pragma unroll
  for (int i0 = 0; i0 < BCH; i0 += 512)
    if (BCH - i0 >= 512 || tid < BCH - i0) {
      int e = (i0 + tid) * 8;
      int row = e / BK, cg = (e & (BK - 1)) >> 3;
      if (SWIZ) cg ^= (row & 7);
      glds16(&Bk[(size_t)(n0 + row) * K + (cg << 3)], &Bs[(i0 + (tid & ~63)) * 8]);
    }
  for (int kt = 0; kt < nk; ++kt) {
    int cur = kt & 1;
    __syncthreads();
    if (kt + 1 < nk) {
      int kb = (kt + 1) * BK;
      int nxt = cur ^ 1;
#pragma unroll
      for (int i0 = 0; i0 < ACH; i0 += 512)
        if (ACH - i0 >= 512 || tid < ACH - i0) {
          int e = (i0 + tid) * 8;
          int row = e / BK, cg = (e & (BK - 1)) >> 3;
          if (SWIZ) cg ^= (row & 7);
          glds16(&Ak[(size_t)(m0 + row) * K + kb + (cg << 3)],
                 &As[nxt * ASZ + (i0 + (tid & ~63)) * 8]);
        }
#pragma unroll
      for (int i0 = 0; i0 < BCH; i0 += 512)
        if (BCH - i0 >= 512 || tid < BCH - i0) {
          int e = (i0 + tid) * 8;
          int row = e / BK, cg = (e & (BK - 1)) >> 3;
          if (SWIZ) cg ^= (row & 7);
          glds16(&Bk[(size_t)(n0 + row) * K + kb + (cg << 3)],
                 &Bs[nxt * BSZ + (i0 + (tid & ~63)) * 8]);
        }
    }
#pragma unroll
    for (int ks = 0; ks < KS; ++ks) {
      s16x8 af[AT], bf[BT];
#pragma unroll
      for (int mt = 0; mt < AT; ++mt) {
        int r = wm * WM + mt * 16 + l15;
        int cg = (ks * 32 + quad * 8) >> 3;
        if (SWIZ) cg ^= (r & 7);
        af[mt] = *(const s16x8*)&As[cur * ASZ + r * BK + (cg << 3)];
      }
#pragma unroll
      for (int nt = 0; nt < BT; ++nt) {
        int r = wn * WN + nt * 16 + l15;
        int cg = (ks * 32 + quad * 8) >> 3;
        if (SWIZ) cg ^= (r & 7);
        bf[nt] = *(const s16x8*)&Bs[cur * BSZ + r * BK + (cg << 3)];
      }
#pragma unroll
      for (int mt = 0; mt < AT; ++mt)
#pragma unroll
        for (int nt = 0; nt < BT; ++nt)
          acc[mt][nt] = __builtin_amdgcn_mfma_f32_16x16x32_bf16(af[mt], bf[nt], acc[mt][nt], 0, 0, 0);
    }
  }

  if (MODE == 0) {
#pragma unroll
    for (int mt = 0; mt < AT; ++mt)
#pragma unroll
      for (int nt = 0; nt < BT; ++nt) {
        int mb = m0 + wm * WM + mt * 16 + quad * 4;
        int n = n0 + wn * WN + nt * 16 + l15;
        int which = n / C_;
        int within = n - which * C_;
        int hd = within >> 6, d = within & 63;
        int bbx = mb >> 11, t = mb & 2047;
        size_t bh = (size_t)(bbx * H_ + hd);
        float b = bias[n];
        if (which == 2) {
          unsigned v01 = (unsigned)f2bf(acc[mt][nt][0] + b) |
                         ((unsigned)f2bf(acc[mt][nt][1] + b) << 16);
          unsigned v23 = (unsigned)f2bf(acc[mt][nt][2] + b) |
                         ((unsigned)f2bf(acc[mt][nt][3] + b) << 16);
          *(uint2*)&vtO[(bh * D_ + d) * T_ + t] = uint2{v01, v23};
        } else {
          unsigned short* dst = (which == 0) ? qO : kO;
#pragma unroll
          for (int r = 0; r < 4; ++r)
            dst[(bh * T_ + t + r) * D_ + d] = f2bf(acc[mt][nt][r] + b);
        }
      }
  } else {
#pragma unroll
    for (int mt = 0; mt < AT; ++mt) {
      int mb = m0 + wm * WM + mt * 16 + quad * 4;
#pragma unroll
      for (int r = 0; r < 4; ++r) {
        int m = mb + r;
#pragma unroll
        for (int nt = 0; nt < BT; ++nt) {
          int n = n0 + wn * WN + nt * 16 + l15;
          if (MODE == 1) {
            float v = acc[mt][nt][r] + bias[n];
            outF[(size_t)m * N + n] = resid[(size_t)m * N + n] + v;
          } else if (MODE == 3) {
            float* P = outF + (size_t)blockIdx.z * M * N;
            P[(size_t)m * N + n] = acc[mt][nt][r];
          } else {
            float v = acc[mt][nt][r] + bias[n];
            float gl = 0.5f * v * (1.f + erff(v * 0.70710678118654752f));
            outB[(size_t)m * N + n] = f2bf(gl);
          }
        }
      }
    }
  }
}

// ---------------- fused causal flash attention (128-key iterations) ---------
__global__ __launch_bounds__(256) void attn_fused(
    const unsigned short* __restrict__ Q, const unsigned short* __restrict__ Kg,
    const unsigned short* __restrict__ Vt, unsigned short* __restrict__ Y) {
  __shared__ __align__(16) unsigned short Ks[128 * 72];
  __shared__ __align__(16) unsigned short Vs[64 * 136];
  __shared__ __align__(16) unsigned short Ps[4][16 * 136];
  int tid = threadIdx.x;
  int wv = tid >> 6, lane = tid & 63, quad = lane >> 4, l15 = lane & 15;
  int l = blockIdx.x;
  int w = l >> 8, c = l & 255;
  int i = c & 31;
  int bh = w * 8 + (c >> 5);
  int qt;
  if (w == 0)      qt = i;
  else if (w == 1) qt = (i + 16) & 31;
  else             qt = (i < 16) ? (30 - 2 * i) : (63 - 2 * i);
  int bbx = bh / H_, hh = bh - bbx * H_;
  int q0 = qt * 64;
  size_t base = (size_t)bh * T_ * D_;
  size_t vbase = (size_t)bh * D_ * T_;
  int qrow = q0 + wv * 16 + l15;
  s16x8 qf0 = *(const s16x8*)&Q[base + (size_t)qrow * D_ + quad * 8];
  s16x8 qf1 = *(const s16x8*)&Q[base + (size_t)qrow * D_ + 32 + quad * 8];
  float lsum[4];
  fx4 oacc[4];
#pragma unroll
  for (int t = 0; t < 4; ++t) {
    lsum[t] = 0.f;
    oacc[t] = fx4{0.f, 0.f, 0.f, 0.f};
  }
  int nDbl = (qt >> 1) + 1;
  int r0s = tid >> 3;          // 0..31
  int c8 = (tid & 7) * 8;      // 0..56
  uint4 ka0, ka1, ka2, ka3, va0, va1, va2, va3;
  {
    const unsigned short* Kp = Kg + base;
    ka0 = *(const uint4*)&Kp[(size_t)r0s * D_ + c8];
    ka1 = *(const uint4*)&Kp[(size_t)(r0s + 32) * D_ + c8];
    ka2 = *(const uint4*)&Kp[(size_t)(r0s + 64) * D_ + c8];
    ka3 = *(const uint4*)&Kp[(size_t)(r0s + 96) * D_ + c8];
    const unsigned short* Vp = Vt + vbase;
    va0 = *(const uint4*)&Vp[(size_t)r0s * T_ + c8];
    va1 = *(const uint4*)&Vp[(size_t)r0s * T_ + 64 + c8];
    va2 = *(const uint4*)&Vp[(size_t)(r0s + 32) * T_ + c8];
    va3 = *(const uint4*)&Vp[(size_t)(r0s + 32) * T_ + 64 + c8];
  }
  unsigned short* pw = &Ps[wv][0];
  for (int kb = 0; kb < nDbl; ++kb) {
    int k0 = kb * 128;
    __syncthreads();
    *(uint4*)&Ks[r0s * 72 + c8] = ka0;
    *(uint4*)&Ks[(r0s + 32) * 72 + c8] = ka1;
    *(uint4*)&Ks[(r0s + 64) * 72 + c8] = ka2;
    *(uint4*)&Ks[(r0s + 96) * 72 + c8] = ka3;
    *(uint4*)&Vs[r0s * 136 + c8] = va0;
    *(uint4*)&Vs[r0s * 136 + 64 + c8] = va1;
    *(uint4*)&Vs[(r0s + 32) * 136 + c8] = va2;
    *(uint4*)&Vs[(r0s + 32) * 136 + 64 + c8] = va3;
    __syncthreads();
    if (kb + 1 < nDbl) {
      int kn = k0 + 128;
      const unsigned short* Kp = Kg + base + (size_t)kn * D_;
      ka0 = *(const uint4*)&Kp[(size_t)r0s * D_ + c8];
      ka1 = *(const uint4*)&Kp[(size_t)(r0s + 32) * D_ + c8];
      ka2 = *(const uint4*)&Kp[(size_t)(r0s + 64) * D_ + c8];
      ka3 = *(const uint4*)&Kp[(size_t)(r0s + 96) * D_ + c8];
      const unsigned short* Vp = Vt + vbase + kn;
      va0 = *(const uint4*)&Vp[(size_t)r0s * T_ + c8];
      va1 = *(const uint4*)&Vp[(size_t)r0s * T_ + 64 + c8];
      va2 = *(const uint4*)&Vp[(size_t)(r0s + 32) * T_ + c8];
      va3 = *(const uint4*)&Vp[(size_t)(r0s + 32) * T_ + 64 + c8];
    }
    fx4 sc[8];
#pragma unroll
    for (int nt = 0; nt < 8; ++nt) {
      sc[nt] = fx4{0.f, 0.f, 0.f, 0.f};
      s16x8 kf0 = *(const s16x8*)&Ks[(nt * 16 + l15) * 72 + quad * 8];
      s16x8 kf1 = *(const s16x8*)&Ks[(nt * 16 + l15) * 72 + 32 + quad * 8];
      sc[nt] = __builtin_amdgcn_mfma_f32_16x16x32_bf16(qf0, kf0, sc[nt], 0, 0, 0);
      sc[nt] = __builtin_amdgcn_mfma_f32_16x16x32_bf16(qf1, kf1, sc[nt], 0, 0, 0);
    }
#pragma unroll
    for (int nt = 0; nt < 8; ++nt)
#pragma unroll
      for (int r = 0; r < 4; ++r) {
        int key = k0 + nt * 16 + l15;
        int row = q0 + wv * 16 + quad * 4 + r;
        float p = (key > row) ? 0.f : __expf(sc[nt][r] * 0.125f);
        lsum[r] += p;
        pw[(quad * 4 + r) * 136 + nt * 16 + l15] = f2bf_trunc(p);
      }
    s16x8 pa[4];
#pragma unroll
    for (int ch = 0; ch < 4; ++ch)
      pa[ch] = *(const s16x8*)&pw[l15 * 136 + ch * 32 + quad * 8];
#pragma unroll
    for (int nt = 0; nt < 4; ++nt) {
#pragma unroll
      for (int ch = 0; ch < 4; ++ch) {
        s16x8 vf = *(const s16x8*)&Vs[(nt * 16 + l15) * 136 + ch * 32 + quad * 8];
        oacc[nt] = __builtin_amdgcn_mfma_f32_16x16x32_bf16(pa[ch], vf, oacc[nt], 0, 0, 0);
      }
    }
  }
#pragma unroll
  for (int r = 0; r < 4; ++r) {
#pragma unroll
    for (int off = 1; off < 16; off <<= 1) lsum[r] += __shfl_xor(lsum[r], off);
  }
#pragma unroll
  for (int nt = 0; nt < 4; ++nt)
#pragma unroll
    for (int r = 0; r < 4; ++r) {
      float o = oacc[nt][r] / lsum[r];
      int token = bbx * T_ + q0 + wv * 16 + quad * 4 + r;
      Y[(size_t)token * C_ + hh * D_ + nt * 16 + l15] = f2bf(o);
    }
}

// ---------------- launcher --------------------------------------------------
extern "C" void kernel_launch(void* const* d_in, const int* in_sizes, int n_in,
                              void* d_out, int out_size, void* d_ws, size_t ws_size,
                              hipStream_t stream) {
  const float* x      = (const float*)d_in[0];
  const float* ln1g   = (const float*)d_in[1];
  const float* ln1b   = (const float*)d_in[2];
  const float* Wattn  = (const float*)d_in[3];
  const float* battn  = (const float*)d_in[4];
  const float* Wcproj = (const float*)d_in[5];
  const float* bcproj = (const float*)d_in[6];
  const float* ln2g   = (const float*)d_in[7];
  const float* ln2b   = (const float*)d_in[8];
  const float* Wfc    = (const float*)d_in[9];
  const float* bfc    = (const float*)d_in[10];
  const float* Wmproj = (const float*)d_in[11];
  const float* bmproj = (const float*)d_in[12];
  float* out = (float*)d_out;
  char* ws = (char*)d_ws;

  unsigned short* WattnT  = (unsigned short*)(ws + 0);          // 2304x768 bf16
  unsigned short* WcprojT = (unsigned short*)(ws + 3538944);    // 768x768
  unsigned short* WfcT    = (unsigned short*)(ws + 4718592);    // 3072x768
  unsigned short* WmprojT = (unsigned short*)(ws + 9437184);    // 768x3072
  unsigned short* hbuf    = (unsigned short*)(ws + 14155776);   // 4096x768 bf16
  unsigned short* Qb      = (unsigned short*)(ws + 20447232);   // [24,2048,64]
  unsigned short* Kb      = (unsigned short*)(ws + 26738688);   // [24,2048,64]
  unsigned short* Vtb     = (unsigned short*)(ws + 33030144);   // [24,64,2048]
  unsigned short* Yb      = (unsigned short*)(ws + 39321600);   // 4096x768 bf16
  float*          x1      = (float*)(ws + 45613056);            // 4096x768 fp32
  unsigned short* Ab      = (unsigned short*)(ws + 58195968);   // 4096x3072 bf16
  // split-K partials overlay Qb..Yb (dead after cproj): 2 x 4096x768 fp32
  float*          Pbuf    = (float*)(ws + 20447232);

  prep<<<11008, 256, 0, stream>>>(Wattn, Wcproj, Wfc, Wmproj,
                                  WattnT, WcprojT, WfcT, WmprojT,
                                  x, ln1g, ln1b, hbuf);

  // qkv: BM=128 BN=96 BK=32, 512-thread blocks -> 768 blocks, 24 waves/CU
  gemm_db<128, 96, 32, 0><<<dim3(24, 32), 512, 0, stream>>>(
      hbuf, WattnT, battn, nullptr, nullptr, nullptr, Qb, Kb, Vtb,
      4096, 2304, 768, 768);

  attn_fused<<<768, 256, 0, stream>>>(Qb, Kb, Vtb, Yb);

  // cproj: BM=128 BN=64 BK=64 swizzled, 384 blocks of 8 waves
  gemm_db<128, 64, 64, 1><<<dim3(32, 12), 512, 0, stream>>>(
      Yb, WcprojT, bcproj, x, x1, nullptr, nullptr, nullptr, nullptr,
      4096, 768, 768, 768);

  layernorm_bf16<<<4096, 256, 0, stream>>>(x1, ln2g, ln2b, hbuf);

  // fc: BM=128 BN=128 BK=32, erf-gelu epilogue, 8-wave blocks
  gemm_db<128, 128, 32, 2><<<dim3(24, 32), 512, 0, stream>>>(
      hbuf, WfcT, bfc, nullptr, nullptr, Ab, nullptr, nullptr, nullptr,
      4096, 3072, 768, 768);

  // mproj split-K=2: 768 blocks of 8 waves, K chunks of 1536
  gemm_db<128, 64, 64, 3><<<dim3(32, 12, 2), 512, 0, stream>>>(
      Ab, WmprojT, bmproj, nullptr, Pbuf, nullptr, nullptr, nullptr, nullptr,
      4096, 768, 3072, 1536);

  // out = x1 + P0 + P1 + bias  (786432 float4 / 256 per block = 3072 blocks)
  reduce_out<<<3072, 256, 0, stream>>>(x1, Pbuf, bmproj, out);
}